// Round 5
// baseline (636.934 us; speedup 1.0000x reference)
//
#include <hip/hip_runtime.h>
#include <hip/hip_bf16.h>

// HeteroGCNConv: 3-layer GCN, N=100000, E=1600000, D=128, f32.
// R4: un-fuse agg+gemm (fusion barrier-coupled gather imbalance: 175 vs 143us);
//     build chain: scan_add folded into consumers (PBLK==256 trick),
//     pkey/pw merged into one int2 stream, zero memsets.

#define D128 128
#define PBLK 256          // partition blocks; MUST equal 256 (scan-fold trick)
#define BUCKET_SHIFT 8
#define DCAP 7168         // staged edges per bucket in pass D (57KB LDS)
#define GR 16

__device__ __forceinline__ float elu1(float x) {
    return x > 0.f ? x : (expf(x) - 1.f);
}

// Pass A: per-block coarse-bucket histograms for BOTH dst and src.
__global__ __launch_bounds__(256) void part_hist2(
    const int* __restrict__ src, const int* __restrict__ dst,
    int* __restrict__ histT2, int E, int nb, int chunk, int hlen) {
    extern __shared__ int sh[];  // 2*nb ints
    for (int i = threadIdx.x; i < 2 * nb; i += 256) sh[i] = 0;
    __syncthreads();
    int b = blockIdx.x;
    int beg = b * chunk, end = min(E, beg + chunk);
    for (int e = beg + threadIdx.x; e < end; e += 256) {
        atomicAdd(&sh[dst[e] >> BUCKET_SHIFT], 1);
        atomicAdd(&sh[nb + (src[e] >> BUCKET_SHIFT)], 1);
    }
    __syncthreads();
    for (int i = threadIdx.x; i < nb; i += 256)
        histT2[i * PBLK + b] = sh[i];
    for (int i = threadIdx.x; i < nb; i += 256)
        histT2[hlen + i * PBLK + b] = sh[nb + i];
}

// Per-256-chunk exclusive scan; chunk sums to blockSums. (No final add pass:
// consumers add bsums[chunk] themselves, since chunk index == row index.)
__global__ __launch_bounds__(256) void scan_block(
    const int* __restrict__ in, int* __restrict__ out,
    int* __restrict__ blockSums, int n) {
    __shared__ int tmp[256];
    int gid = blockIdx.x * 256 + threadIdx.x;
    int v = (gid < n) ? in[gid] : 0;
    tmp[threadIdx.x] = v;
    __syncthreads();
    for (int off = 1; off < 256; off <<= 1) {
        int t = (threadIdx.x >= off) ? tmp[threadIdx.x - off] : 0;
        __syncthreads();
        tmp[threadIdx.x] += t;
        __syncthreads();
    }
    if (gid < n) out[gid] = tmp[threadIdx.x] - v;  // exclusive within chunk
    if (threadIdx.x == 255) blockSums[blockIdx.x] = tmp[255];
}

__global__ __launch_bounds__(1024) void scan_sums(int* __restrict__ bsums, int nb) {
    __shared__ int tmp[1024];
    int v = (threadIdx.x < nb) ? bsums[threadIdx.x] : 0;
    tmp[threadIdx.x] = v;
    __syncthreads();
    for (int off = 1; off < 1024; off <<= 1) {
        int t = (threadIdx.x >= off) ? tmp[threadIdx.x - off] : 0;
        __syncthreads();
        tmp[threadIdx.x] += t;
        __syncthreads();
    }
    if (threadIdx.x < nb) bsums[threadIdx.x] = tmp[threadIdx.x] - v;  // exclusive
}

// Pass C: stable partition by dst (pkw) AND by src (skw), one pass.
__global__ __launch_bounds__(256) void part_scatter2(
    const int* __restrict__ src, const int* __restrict__ dst,
    const float* __restrict__ w, const int* __restrict__ offsT2,
    const int* __restrict__ bsums,
    int2* __restrict__ pkw, int2* __restrict__ skw,
    int E, int nb, int chunk, int hlen) {
    extern __shared__ int cur[];  // 2*nb ints
    int b = blockIdx.x;
    for (int i = threadIdx.x; i < nb; i += 256)
        cur[i] = offsT2[i * PBLK + b] + bsums[i];
    for (int i = threadIdx.x; i < nb; i += 256)
        cur[nb + i] = offsT2[hlen + i * PBLK + b] + bsums[nb + i] - E;
    __syncthreads();
    int beg = b * chunk, end = min(E, beg + chunk);
    for (int e = beg + threadIdx.x; e < end; e += 256) {
        int d = dst[e];
        int s = src[e];
        int wv = __float_as_int(w[e]);
        int kd = d >> BUCKET_SHIFT;
        int pos = atomicAdd(&cur[kd], 1);
        pkw[pos] = make_int2((int)((unsigned)s | ((unsigned)(d & 255) << 24)), wv);
        int ks = s >> BUCKET_SHIFT;
        int posS = atomicAdd(&cur[nb + ks], 1);
        skw[posS] = make_int2(s & 255, wv);
    }
}

// Weighted out-degree per node: one block per src bucket, LDS float sums.
__global__ __launch_bounds__(256) void bucket_sumS(
    const int2* __restrict__ skw, const int* __restrict__ offsT2,
    const int* __restrict__ bsums,
    float* __restrict__ deg_src, int E, int nb, int N, int hlen) {
    __shared__ float wsum[256];
    int k = blockIdx.x;
    int base = offsT2[hlen + k * PBLK] + bsums[nb + k] - E;
    int end = (k + 1 < nb) ? (offsT2[hlen + (k + 1) * PBLK] + bsums[nb + k + 1] - E) : E;
    int t = threadIdx.x;
    wsum[t] = 0.f;
    __syncthreads();
    for (int i = base + t; i < end; i += 256) {
        int2 v = skw[i];
        atomicAdd(&wsum[v.x], __int_as_float(v.y));
    }
    __syncthreads();
    int node = (k << BUCKET_SHIFT) + t;
    if (node < N) deg_src[node] = wsum[t];
}

// Pass D: one block per dst bucket. LDS histogram -> per-node counts +
// weighted in-degree; LDS scan -> row_start; reorder; write edata{src,nw}.
__global__ __launch_bounds__(256) void bucket_build(
    const int2* __restrict__ pkw, const int* __restrict__ offsT,
    const int* __restrict__ bsums, const float* __restrict__ deg_src,
    int* __restrict__ row_start, int2* __restrict__ edata,
    int E, int nb, int N) {
    __shared__ int cnt[256];
    __shared__ float wsum[256];
    __shared__ int loc[256];
    __shared__ int cur2[256];
    extern __shared__ int2 stage[];  // DCAP int2

    int k = blockIdx.x;
    int base = offsT[k * PBLK] + bsums[k];
    int end = (k + 1 < nb) ? (offsT[(k + 1) * PBLK] + bsums[k + 1]) : E;
    int m = end - base;
    int t = threadIdx.x;
    cnt[t] = 0;
    wsum[t] = 0.f;
    __syncthreads();
    bool staged = (m <= DCAP);
    for (int i = t; i < m; i += 256) {
        int2 kw = pkw[base + i];
        if (staged) stage[i] = kw;
        int dl = (unsigned)kw.x >> 24;
        atomicAdd(&cnt[dl], 1);
        atomicAdd(&wsum[dl], __int_as_float(kw.y));
    }
    __syncthreads();
    int v = cnt[t];
    loc[t] = v;
    __syncthreads();
    for (int off = 1; off < 256; off <<= 1) {
        int tv = (t >= off) ? loc[t - off] : 0;
        __syncthreads();
        loc[t] += tv;
        __syncthreads();
    }
    int excl = loc[t] - v;
    loc[t] = excl;
    cur2[t] = 0;
    int node = (k << BUCKET_SHIFT) + t;
    if (node < N) row_start[node] = base + excl;
    if (k == 0 && t == 0) row_start[N] = E;
    __syncthreads();
    for (int i = t; i < m; i += 256) {
        int2 kw = staged ? stage[i] : pkw[base + i];
        int dl = (unsigned)kw.x >> 24;
        int s = kw.x & 0xFFFFFF;
        int pos = base + loc[dl] + atomicAdd(&cur2[dl], 1);
        float nw = __int_as_float(kw.y) * rsqrtf(deg_src[s] * wsum[dl]);
        edata[pos] = make_int2(s, __float_as_int(nw));
    }
}

// out[r] = A[r] @ W  (W is [128][128] row-major). Row-local => in-place safe.
__global__ __launch_bounds__(256) void gemm128(
    const float* __restrict__ A, const float* __restrict__ W,
    float* __restrict__ out, int n, int nblk) {
    __shared__ float rows[GR][D128];
    const int tid = threadIdx.x;
    const int j = tid & 127;
    const int rg = tid >> 7;
    for (int rb = blockIdx.x; rb < nblk; rb += gridDim.x) {
        const int r0 = rb * GR;
        __syncthreads();
        for (int f = tid; f < GR * 32; f += 256) {
            int rr = f >> 5, ch = f & 31;
            int grow = r0 + rr;
            float4 v = make_float4(0.f, 0.f, 0.f, 0.f);
            if (grow < n) v = ((const float4*)(A + (size_t)grow * D128))[ch];
            ((float4*)&rows[rr][0])[ch] = v;
        }
        __syncthreads();
        float acc[8] = {0.f, 0.f, 0.f, 0.f, 0.f, 0.f, 0.f, 0.f};
        for (int k = 0; k < D128; k += 4) {
            float w0 = W[(k + 0) * D128 + j];
            float w1 = W[(k + 1) * D128 + j];
            float w2 = W[(k + 2) * D128 + j];
            float w3 = W[(k + 3) * D128 + j];
#pragma unroll
            for (int m = 0; m < 8; ++m) {
                float4 r = *((const float4*)&rows[rg + 2 * m][k]);
                acc[m] = fmaf(r.x, w0, acc[m]);
                acc[m] = fmaf(r.y, w1, acc[m]);
                acc[m] = fmaf(r.z, w2, acc[m]);
                acc[m] = fmaf(r.w, w3, acc[m]);
            }
        }
#pragma unroll
        for (int m = 0; m < 8; ++m) {
            int rr = r0 + rg + 2 * m;
            if (rr < n) out[(size_t)rr * D128 + j] = acc[m];
        }
    }
}

// Standalone aggregate (+bias, ELU): one wave per dst node.
// 2 edges x 32 float4-chunks per iter, unrolled x4 (4 rows in flight/half).
__global__ __launch_bounds__(256) void aggregate(
    const float* __restrict__ h, const int* __restrict__ rs,
    const int2* __restrict__ edata,
    const float* __restrict__ bias, float* __restrict__ out, int n) {
    int wave = threadIdx.x >> 6;
    int lane = threadIdx.x & 63;
    int node = blockIdx.x * 4 + wave;
    if (node >= n) return;
    int beg = rs[node], end = rs[node + 1];
    int half = lane >> 5, c = lane & 31;
    float4 a0 = make_float4(0.f, 0.f, 0.f, 0.f);
    float4 a1 = a0, a2 = a0, a3 = a0;
    int i = beg + half;
    for (; i + 6 < end; i += 8) {
        int2 e0 = edata[i];
        int2 e1 = edata[i + 2];
        int2 e2 = edata[i + 4];
        int2 e3 = edata[i + 6];
        float4 r0 = ((const float4*)(h + (size_t)e0.x * D128))[c];
        float4 r1 = ((const float4*)(h + (size_t)e1.x * D128))[c];
        float4 r2 = ((const float4*)(h + (size_t)e2.x * D128))[c];
        float4 r3 = ((const float4*)(h + (size_t)e3.x * D128))[c];
        float w0 = __int_as_float(e0.y), w1 = __int_as_float(e1.y);
        float w2 = __int_as_float(e2.y), w3 = __int_as_float(e3.y);
        a0.x = fmaf(r0.x, w0, a0.x); a0.y = fmaf(r0.y, w0, a0.y);
        a0.z = fmaf(r0.z, w0, a0.z); a0.w = fmaf(r0.w, w0, a0.w);
        a1.x = fmaf(r1.x, w1, a1.x); a1.y = fmaf(r1.y, w1, a1.y);
        a1.z = fmaf(r1.z, w1, a1.z); a1.w = fmaf(r1.w, w1, a1.w);
        a2.x = fmaf(r2.x, w2, a2.x); a2.y = fmaf(r2.y, w2, a2.y);
        a2.z = fmaf(r2.z, w2, a2.z); a2.w = fmaf(r2.w, w2, a2.w);
        a3.x = fmaf(r3.x, w3, a3.x); a3.y = fmaf(r3.y, w3, a3.y);
        a3.z = fmaf(r3.z, w3, a3.z); a3.w = fmaf(r3.w, w3, a3.w);
    }
    for (; i < end; i += 2) {
        int2 e0 = edata[i];
        float4 r0 = ((const float4*)(h + (size_t)e0.x * D128))[c];
        float w0 = __int_as_float(e0.y);
        a0.x = fmaf(r0.x, w0, a0.x); a0.y = fmaf(r0.y, w0, a0.y);
        a0.z = fmaf(r0.z, w0, a0.z); a0.w = fmaf(r0.w, w0, a0.w);
    }
    a0.x += a1.x + a2.x + a3.x;
    a0.y += a1.y + a2.y + a3.y;
    a0.z += a1.z + a2.z + a3.z;
    a0.w += a1.w + a2.w + a3.w;
    a0.x += __shfl_xor(a0.x, 32);
    a0.y += __shfl_xor(a0.y, 32);
    a0.z += __shfl_xor(a0.z, 32);
    a0.w += __shfl_xor(a0.w, 32);
    if (half == 0) {
        float4 bb = ((const float4*)bias)[c];
        float4 o;
        o.x = elu1(a0.x + bb.x);
        o.y = elu1(a0.y + bb.y);
        o.z = elu1(a0.z + bb.z);
        o.w = elu1(a0.w + bb.w);
        ((float4*)(out + (size_t)node * D128))[c] = o;
    }
}

extern "C" void kernel_launch(void* const* d_in, const int* in_sizes, int n_in,
                              void* d_out, int out_size, void* d_ws, size_t ws_size,
                              hipStream_t stream) {
    const float* x   = (const float*)d_in[0];
    const float* ew  = (const float*)d_in[1];
    const float* W   = (const float*)d_in[2];
    const float* b   = (const float*)d_in[3];
    const int*   src = (const int*)d_in[4];
    const int*   dst = (const int*)d_in[5];
    float* out = (float*)d_out;

    const int N = in_sizes[0] / D128;
    const int E = in_sizes[1];
    const int L = in_sizes[2] / (D128 * D128);   // == 3 here
    const int nb = (N + 255) >> BUCKET_SHIFT;
    const int hlen = nb * PBLK;

    char* ws = (char*)d_ws;
    size_t off = 0;
    auto take = [&](size_t bytes) {
        void* p = ws + off;
        off = (off + bytes + 255) & ~(size_t)255;
        return p;
    };
    float* deg_src = (float*)take((size_t)N * 4);
    int*   histT2  = (int*)take((size_t)2 * hlen * 4);
    int*   offsT2  = (int*)take((size_t)2 * hlen * 4);
    int*   bsums   = (int*)take(1024 * 4);
    int*   rstart  = (int*)take((size_t)(N + 1) * 4);
    int2*  edata   = (int2*)take((size_t)E * 8);
    float* B0      = (float*)take((size_t)N * D128 * 4);
    // partition scratch aliases B0 (dead before gemm0 writes B0):
    int2* pkw = (int2*)B0;                     // E * 8
    int2* skw = (int2*)(B0 + 2 * (size_t)E);   // E * 8  (tot 25.6MB <= 51.2MB)

    const int chunk = (E + PBLK - 1) / PBLK;
    const int sb2 = (2 * hlen + 255) / 256;    // == 2*nb <= 1024
    const size_t part_lds = (size_t)2 * nb * 4;
    const size_t dcap_lds = (size_t)DCAP * 8;

    part_hist2<<<PBLK, 256, part_lds, stream>>>(src, dst, histT2, E, nb, chunk, hlen);
    scan_block<<<sb2, 256, 0, stream>>>(histT2, offsT2, bsums, 2 * hlen);
    scan_sums<<<1, 1024, 0, stream>>>(bsums, sb2);
    part_scatter2<<<PBLK, 256, part_lds, stream>>>(src, dst, ew, offsT2, bsums,
                                                   pkw, skw, E, nb, chunk, hlen);
    bucket_sumS<<<nb, 256, 0, stream>>>(skw, offsT2, bsums, deg_src, E, nb, N, hlen);
    bucket_build<<<nb, 256, dcap_lds, stream>>>(pkw, offsT2, bsums, deg_src,
                                                rstart, edata, E, nb, N);

    const int nblk = (N + GR - 1) / GR;
    const int gemm_grid = nblk < 2048 ? nblk : 2048;
    const int agg_grid = (N + 3) / 4;

    // layer 0: x @ W0 -> B0 ; agg(+b0,ELU) -> out
    gemm128<<<gemm_grid, 256, 0, stream>>>(x, W, B0, N, nblk);
    aggregate<<<agg_grid, 256, 0, stream>>>(B0, rstart, edata, b, out, N);
    // layer 1: out @ W1 -> out (in-place) ; agg(+b1,ELU) -> B0
    gemm128<<<gemm_grid, 256, 0, stream>>>(out, W + D128 * D128, out, N, nblk);
    aggregate<<<agg_grid, 256, 0, stream>>>(out, rstart, edata, b + D128, B0, N);
    // layer 2: B0 @ W2 -> B0 (in-place) ; agg(+b2,ELU) -> out
    gemm128<<<gemm_grid, 256, 0, stream>>>(B0, W + 2 * D128 * D128, B0, N, nblk);
    aggregate<<<agg_grid, 256, 0, stream>>>(B0, rstart, edata, b + 2 * D128, out, N);
}

// Round 6
// 512.505 us; speedup vs baseline: 1.2428x; 1.2428x over previous
//
#include <hip/hip_runtime.h>
#include <hip/hip_bf16.h>

// HeteroGCNConv: 3-layer GCN, N=100000, E=1600000, D=128, f32.
// R5: gemm outputs bf16 tables H (halves aggregate's gather bytes — the
//     dominant L2-fill traffic, 380MB/call); aggregate accumulates f32,
//     writes f32 (+bias+ELU) to d_out in-place each layer. Build scratch
//     (pkw/skw) aliases H. ws ~42MB.

#define D128 128
#define PBLK 256          // partition blocks; MUST equal 256 (scan-fold trick)
#define BUCKET_SHIFT 8
#define DCAP 7168         // staged edges per bucket in pass D (57KB LDS)
#define GR 16

__device__ __forceinline__ float elu1(float x) {
    return x > 0.f ? x : (expf(x) - 1.f);
}

// Pass A: per-block coarse-bucket histograms for BOTH dst and src.
__global__ __launch_bounds__(256) void part_hist2(
    const int* __restrict__ src, const int* __restrict__ dst,
    int* __restrict__ histT2, int E, int nb, int chunk, int hlen) {
    extern __shared__ int sh[];  // 2*nb ints
    for (int i = threadIdx.x; i < 2 * nb; i += 256) sh[i] = 0;
    __syncthreads();
    int b = blockIdx.x;
    int beg = b * chunk, end = min(E, beg + chunk);
    for (int e = beg + threadIdx.x; e < end; e += 256) {
        atomicAdd(&sh[dst[e] >> BUCKET_SHIFT], 1);
        atomicAdd(&sh[nb + (src[e] >> BUCKET_SHIFT)], 1);
    }
    __syncthreads();
    for (int i = threadIdx.x; i < nb; i += 256)
        histT2[i * PBLK + b] = sh[i];
    for (int i = threadIdx.x; i < nb; i += 256)
        histT2[hlen + i * PBLK + b] = sh[nb + i];
}

// Per-256-chunk exclusive scan; chunk sums to blockSums. (No final add pass:
// consumers add bsums[chunk] themselves, since chunk index == row index.)
__global__ __launch_bounds__(256) void scan_block(
    const int* __restrict__ in, int* __restrict__ out,
    int* __restrict__ blockSums, int n) {
    __shared__ int tmp[256];
    int gid = blockIdx.x * 256 + threadIdx.x;
    int v = (gid < n) ? in[gid] : 0;
    tmp[threadIdx.x] = v;
    __syncthreads();
    for (int off = 1; off < 256; off <<= 1) {
        int t = (threadIdx.x >= off) ? tmp[threadIdx.x - off] : 0;
        __syncthreads();
        tmp[threadIdx.x] += t;
        __syncthreads();
    }
    if (gid < n) out[gid] = tmp[threadIdx.x] - v;  // exclusive within chunk
    if (threadIdx.x == 255) blockSums[blockIdx.x] = tmp[255];
}

__global__ __launch_bounds__(1024) void scan_sums(int* __restrict__ bsums, int nb) {
    __shared__ int tmp[1024];
    int v = (threadIdx.x < nb) ? bsums[threadIdx.x] : 0;
    tmp[threadIdx.x] = v;
    __syncthreads();
    for (int off = 1; off < 1024; off <<= 1) {
        int t = (threadIdx.x >= off) ? tmp[threadIdx.x - off] : 0;
        __syncthreads();
        tmp[threadIdx.x] += t;
        __syncthreads();
    }
    if (threadIdx.x < nb) bsums[threadIdx.x] = tmp[threadIdx.x] - v;  // exclusive
}

// Pass C: stable partition by dst (pkw) AND by src (skw), one pass.
__global__ __launch_bounds__(256) void part_scatter2(
    const int* __restrict__ src, const int* __restrict__ dst,
    const float* __restrict__ w, const int* __restrict__ offsT2,
    const int* __restrict__ bsums,
    int2* __restrict__ pkw, int2* __restrict__ skw,
    int E, int nb, int chunk, int hlen) {
    extern __shared__ int cur[];  // 2*nb ints
    int b = blockIdx.x;
    for (int i = threadIdx.x; i < nb; i += 256)
        cur[i] = offsT2[i * PBLK + b] + bsums[i];
    for (int i = threadIdx.x; i < nb; i += 256)
        cur[nb + i] = offsT2[hlen + i * PBLK + b] + bsums[nb + i] - E;
    __syncthreads();
    int beg = b * chunk, end = min(E, beg + chunk);
    for (int e = beg + threadIdx.x; e < end; e += 256) {
        int d = dst[e];
        int s = src[e];
        int wv = __float_as_int(w[e]);
        int kd = d >> BUCKET_SHIFT;
        int pos = atomicAdd(&cur[kd], 1);
        pkw[pos] = make_int2((int)((unsigned)s | ((unsigned)(d & 255) << 24)), wv);
        int ks = s >> BUCKET_SHIFT;
        int posS = atomicAdd(&cur[nb + ks], 1);
        skw[posS] = make_int2(s & 255, wv);
    }
}

// Weighted out-degree per node: one block per src bucket, LDS float sums.
__global__ __launch_bounds__(256) void bucket_sumS(
    const int2* __restrict__ skw, const int* __restrict__ offsT2,
    const int* __restrict__ bsums,
    float* __restrict__ deg_src, int E, int nb, int N, int hlen) {
    __shared__ float wsum[256];
    int k = blockIdx.x;
    int base = offsT2[hlen + k * PBLK] + bsums[nb + k] - E;
    int end = (k + 1 < nb) ? (offsT2[hlen + (k + 1) * PBLK] + bsums[nb + k + 1] - E) : E;
    int t = threadIdx.x;
    wsum[t] = 0.f;
    __syncthreads();
    for (int i = base + t; i < end; i += 256) {
        int2 v = skw[i];
        atomicAdd(&wsum[v.x], __int_as_float(v.y));
    }
    __syncthreads();
    int node = (k << BUCKET_SHIFT) + t;
    if (node < N) deg_src[node] = wsum[t];
}

// Pass D: one block per dst bucket. LDS histogram -> per-node counts +
// weighted in-degree; LDS scan -> row_start; reorder; write edata{src,nw}.
__global__ __launch_bounds__(256) void bucket_build(
    const int2* __restrict__ pkw, const int* __restrict__ offsT,
    const int* __restrict__ bsums, const float* __restrict__ deg_src,
    int* __restrict__ row_start, int2* __restrict__ edata,
    int E, int nb, int N) {
    __shared__ int cnt[256];
    __shared__ float wsum[256];
    __shared__ int loc[256];
    __shared__ int cur2[256];
    extern __shared__ int2 stage[];  // DCAP int2

    int k = blockIdx.x;
    int base = offsT[k * PBLK] + bsums[k];
    int end = (k + 1 < nb) ? (offsT[(k + 1) * PBLK] + bsums[k + 1]) : E;
    int m = end - base;
    int t = threadIdx.x;
    cnt[t] = 0;
    wsum[t] = 0.f;
    __syncthreads();
    bool staged = (m <= DCAP);
    for (int i = t; i < m; i += 256) {
        int2 kw = pkw[base + i];
        if (staged) stage[i] = kw;
        int dl = (unsigned)kw.x >> 24;
        atomicAdd(&cnt[dl], 1);
        atomicAdd(&wsum[dl], __int_as_float(kw.y));
    }
    __syncthreads();
    int v = cnt[t];
    loc[t] = v;
    __syncthreads();
    for (int off = 1; off < 256; off <<= 1) {
        int tv = (t >= off) ? loc[t - off] : 0;
        __syncthreads();
        loc[t] += tv;
        __syncthreads();
    }
    int excl = loc[t] - v;
    loc[t] = excl;
    cur2[t] = 0;
    int node = (k << BUCKET_SHIFT) + t;
    if (node < N) row_start[node] = base + excl;
    if (k == 0 && t == 0) row_start[N] = E;
    __syncthreads();
    for (int i = t; i < m; i += 256) {
        int2 kw = staged ? stage[i] : pkw[base + i];
        int dl = (unsigned)kw.x >> 24;
        int s = kw.x & 0xFFFFFF;
        int pos = base + loc[dl] + atomicAdd(&cur2[dl], 1);
        float nw = __int_as_float(kw.y) * rsqrtf(deg_src[s] * wsum[dl]);
        edata[pos] = make_int2(s, __float_as_int(nw));
    }
}

// Hb[r] = bf16(A[r] @ W)  (W is [128][128] row-major, f32 in, bf16 out).
__global__ __launch_bounds__(256) void gemm128_bf16(
    const float* __restrict__ A, const float* __restrict__ W,
    __hip_bfloat16* __restrict__ Hb, int n, int nblk) {
    __shared__ float rows[GR][D128];
    const int tid = threadIdx.x;
    const int j = tid & 127;
    const int rg = tid >> 7;
    for (int rb = blockIdx.x; rb < nblk; rb += gridDim.x) {
        const int r0 = rb * GR;
        __syncthreads();
        for (int f = tid; f < GR * 32; f += 256) {
            int rr = f >> 5, ch = f & 31;
            int grow = r0 + rr;
            float4 v = make_float4(0.f, 0.f, 0.f, 0.f);
            if (grow < n) v = ((const float4*)(A + (size_t)grow * D128))[ch];
            ((float4*)&rows[rr][0])[ch] = v;
        }
        __syncthreads();
        float acc[8] = {0.f, 0.f, 0.f, 0.f, 0.f, 0.f, 0.f, 0.f};
        for (int k = 0; k < D128; k += 4) {
            float w0 = W[(k + 0) * D128 + j];
            float w1 = W[(k + 1) * D128 + j];
            float w2 = W[(k + 2) * D128 + j];
            float w3 = W[(k + 3) * D128 + j];
#pragma unroll
            for (int m = 0; m < 8; ++m) {
                float4 r = *((const float4*)&rows[rg + 2 * m][k]);
                acc[m] = fmaf(r.x, w0, acc[m]);
                acc[m] = fmaf(r.y, w1, acc[m]);
                acc[m] = fmaf(r.z, w2, acc[m]);
                acc[m] = fmaf(r.w, w3, acc[m]);
            }
        }
#pragma unroll
        for (int m = 0; m < 8; ++m) {
            int rr = r0 + rg + 2 * m;
            if (rr < n) Hb[(size_t)rr * D128 + j] = __float2bfloat16(acc[m]);
        }
    }
}

// Aggregate from bf16 table (+bias, ELU, f32 out): one wave per dst node.
// 2 edges x 32 x (8B = 4 bf16) per iter, unrolled x4.
__global__ __launch_bounds__(256) void aggregate_bf16(
    const unsigned short* __restrict__ hb, const int* __restrict__ rs,
    const int2* __restrict__ edata,
    const float* __restrict__ bias, float* __restrict__ out, int n) {
    int wave = threadIdx.x >> 6;
    int lane = threadIdx.x & 63;
    int node = blockIdx.x * 4 + wave;
    if (node >= n) return;
    int beg = rs[node], end = rs[node + 1];
    int half = lane >> 5, c = lane & 31;
    float4 a0 = make_float4(0.f, 0.f, 0.f, 0.f);
    float4 a1 = a0, a2 = a0, a3 = a0;
    int i = beg + half;
    for (; i + 6 < end; i += 8) {
        int2 e0 = edata[i];
        int2 e1 = edata[i + 2];
        int2 e2 = edata[i + 4];
        int2 e3 = edata[i + 6];
        uint2 p0 = ((const uint2*)(hb + (size_t)e0.x * D128))[c];
        uint2 p1 = ((const uint2*)(hb + (size_t)e1.x * D128))[c];
        uint2 p2 = ((const uint2*)(hb + (size_t)e2.x * D128))[c];
        uint2 p3 = ((const uint2*)(hb + (size_t)e3.x * D128))[c];
        float w0 = __int_as_float(e0.y), w1 = __int_as_float(e1.y);
        float w2 = __int_as_float(e2.y), w3 = __int_as_float(e3.y);
        a0.x = fmaf(__uint_as_float(p0.x << 16), w0, a0.x);
        a0.y = fmaf(__uint_as_float(p0.x & 0xffff0000u), w0, a0.y);
        a0.z = fmaf(__uint_as_float(p0.y << 16), w0, a0.z);
        a0.w = fmaf(__uint_as_float(p0.y & 0xffff0000u), w0, a0.w);
        a1.x = fmaf(__uint_as_float(p1.x << 16), w1, a1.x);
        a1.y = fmaf(__uint_as_float(p1.x & 0xffff0000u), w1, a1.y);
        a1.z = fmaf(__uint_as_float(p1.y << 16), w1, a1.z);
        a1.w = fmaf(__uint_as_float(p1.y & 0xffff0000u), w1, a1.w);
        a2.x = fmaf(__uint_as_float(p2.x << 16), w2, a2.x);
        a2.y = fmaf(__uint_as_float(p2.x & 0xffff0000u), w2, a2.y);
        a2.z = fmaf(__uint_as_float(p2.y << 16), w2, a2.z);
        a2.w = fmaf(__uint_as_float(p2.y & 0xffff0000u), w2, a2.w);
        a3.x = fmaf(__uint_as_float(p3.x << 16), w3, a3.x);
        a3.y = fmaf(__uint_as_float(p3.x & 0xffff0000u), w3, a3.y);
        a3.z = fmaf(__uint_as_float(p3.y << 16), w3, a3.z);
        a3.w = fmaf(__uint_as_float(p3.y & 0xffff0000u), w3, a3.w);
    }
    for (; i < end; i += 2) {
        int2 e0 = edata[i];
        uint2 p0 = ((const uint2*)(hb + (size_t)e0.x * D128))[c];
        float w0 = __int_as_float(e0.y);
        a0.x = fmaf(__uint_as_float(p0.x << 16), w0, a0.x);
        a0.y = fmaf(__uint_as_float(p0.x & 0xffff0000u), w0, a0.y);
        a0.z = fmaf(__uint_as_float(p0.y << 16), w0, a0.z);
        a0.w = fmaf(__uint_as_float(p0.y & 0xffff0000u), w0, a0.w);
    }
    a0.x += a1.x + a2.x + a3.x;
    a0.y += a1.y + a2.y + a3.y;
    a0.z += a1.z + a2.z + a3.z;
    a0.w += a1.w + a2.w + a3.w;
    a0.x += __shfl_xor(a0.x, 32);
    a0.y += __shfl_xor(a0.y, 32);
    a0.z += __shfl_xor(a0.z, 32);
    a0.w += __shfl_xor(a0.w, 32);
    if (half == 0) {
        float4 bb = ((const float4*)bias)[c];
        float4 o;
        o.x = elu1(a0.x + bb.x);
        o.y = elu1(a0.y + bb.y);
        o.z = elu1(a0.z + bb.z);
        o.w = elu1(a0.w + bb.w);
        ((float4*)(out + (size_t)node * D128))[c] = o;
    }
}

extern "C" void kernel_launch(void* const* d_in, const int* in_sizes, int n_in,
                              void* d_out, int out_size, void* d_ws, size_t ws_size,
                              hipStream_t stream) {
    const float* x   = (const float*)d_in[0];
    const float* ew  = (const float*)d_in[1];
    const float* W   = (const float*)d_in[2];
    const float* b   = (const float*)d_in[3];
    const int*   src = (const int*)d_in[4];
    const int*   dst = (const int*)d_in[5];
    float* out = (float*)d_out;

    const int N = in_sizes[0] / D128;
    const int E = in_sizes[1];
    const int L = in_sizes[2] / (D128 * D128);   // == 3 here
    const int nb = (N + 255) >> BUCKET_SHIFT;
    const int hlen = nb * PBLK;

    char* ws = (char*)d_ws;
    size_t off = 0;
    auto take = [&](size_t bytes) {
        void* p = ws + off;
        off = (off + bytes + 255) & ~(size_t)255;
        return p;
    };
    float* deg_src = (float*)take((size_t)N * 4);
    int*   histT2  = (int*)take((size_t)2 * hlen * 4);
    int*   offsT2  = (int*)take((size_t)2 * hlen * 4);
    int*   bsums   = (int*)take(1024 * 4);
    int*   rstart  = (int*)take((size_t)(N + 1) * 4);
    int2*  edata   = (int2*)take((size_t)E * 8);
    __hip_bfloat16* Hb = (__hip_bfloat16*)take((size_t)N * D128 * 2);
    // partition scratch aliases Hb (dead before gemm0 writes Hb):
    // needs E*16 bytes <= N*256 bytes  (25.6MB == 25.6MB here)
    int2* pkw = (int2*)Hb;                     // E * 8
    int2* skw = ((int2*)Hb) + E;               // E * 8

    const int chunk = (E + PBLK - 1) / PBLK;
    const int sb2 = (2 * hlen + 255) / 256;    // == 2*nb <= 1024
    const size_t part_lds = (size_t)2 * nb * 4;
    const size_t dcap_lds = (size_t)DCAP * 8;

    part_hist2<<<PBLK, 256, part_lds, stream>>>(src, dst, histT2, E, nb, chunk, hlen);
    scan_block<<<sb2, 256, 0, stream>>>(histT2, offsT2, bsums, 2 * hlen);
    scan_sums<<<1, 1024, 0, stream>>>(bsums, sb2);
    part_scatter2<<<PBLK, 256, part_lds, stream>>>(src, dst, ew, offsT2, bsums,
                                                   pkw, skw, E, nb, chunk, hlen);
    bucket_sumS<<<nb, 256, 0, stream>>>(skw, offsT2, bsums, deg_src, E, nb, N, hlen);
    bucket_build<<<nb, 256, dcap_lds, stream>>>(pkw, offsT2, bsums, deg_src,
                                                rstart, edata, E, nb, N);

    const int nblk = (N + GR - 1) / GR;
    const int gemm_grid = nblk < 2048 ? nblk : 2048;
    const int agg_grid = (N + 3) / 4;

    // layer i: A --gemm--> Hb (bf16) --agg(+b_i,ELU)--> d_out (in-place cycle)
    gemm128_bf16<<<gemm_grid, 256, 0, stream>>>(x, W, Hb, N, nblk);
    aggregate_bf16<<<agg_grid, 256, 0, stream>>>((const unsigned short*)Hb, rstart,
                                                 edata, b, out, N);
    for (int l = 1; l < L; ++l) {
        gemm128_bf16<<<gemm_grid, 256, 0, stream>>>(out, W + (size_t)l * D128 * D128,
                                                    Hb, N, nblk);
        aggregate_bf16<<<agg_grid, 256, 0, stream>>>((const unsigned short*)Hb, rstart,
                                                     edata, b + (size_t)l * D128, out, N);
    }
}

// Round 7
// 364.728 us; speedup vs baseline: 1.7463x; 1.4052x over previous
//
#include <hip/hip_runtime.h>
#include <hip/hip_bf16.h>

// HeteroGCNConv: 3-layer GCN, N=100000, E=1600000, D=128, f32.
// R6: GEMM via MFMA bf16 hi/lo split (A@W = Ah@Wh + Ah@Wl + Al@Wh, err ~2^-17).
//     W pre-split into [kc][n][8]-granule bf16 tables; A staged f32->hi/lo in
//     LDS (XOR-row swizzle); mfma_f32_32x32x16_bf16; Hb bf16 out for agg.
//     Build chain + aggregate_bf16 unchanged from R5.

#define D128 128
#define PBLK 256          // partition blocks; MUST equal 256 (scan-fold trick)
#define BUCKET_SHIFT 8
#define DCAP 7168         // staged edges per bucket in pass D (57KB LDS)

typedef __attribute__((ext_vector_type(8))) short s8v;     // 8 bf16 = 4 VGPR
typedef __attribute__((ext_vector_type(16))) float f16v;   // 16 f32 acc

__device__ __forceinline__ float elu1(float x) {
    return x > 0.f ? x : (expf(x) - 1.f);
}

__device__ __forceinline__ unsigned short bf16_rne(float v) {
    unsigned u = __float_as_uint(v);
    return (unsigned short)((u + 0x7fffu + ((u >> 16) & 1u)) >> 16);
}

// ---------------- build chain (unchanged from R5) ----------------

__global__ __launch_bounds__(256) void part_hist2(
    const int* __restrict__ src, const int* __restrict__ dst,
    int* __restrict__ histT2, int E, int nb, int chunk, int hlen) {
    extern __shared__ int sh[];  // 2*nb ints
    for (int i = threadIdx.x; i < 2 * nb; i += 256) sh[i] = 0;
    __syncthreads();
    int b = blockIdx.x;
    int beg = b * chunk, end = min(E, beg + chunk);
    for (int e = beg + threadIdx.x; e < end; e += 256) {
        atomicAdd(&sh[dst[e] >> BUCKET_SHIFT], 1);
        atomicAdd(&sh[nb + (src[e] >> BUCKET_SHIFT)], 1);
    }
    __syncthreads();
    for (int i = threadIdx.x; i < nb; i += 256)
        histT2[i * PBLK + b] = sh[i];
    for (int i = threadIdx.x; i < nb; i += 256)
        histT2[hlen + i * PBLK + b] = sh[nb + i];
}

__global__ __launch_bounds__(256) void scan_block(
    const int* __restrict__ in, int* __restrict__ out,
    int* __restrict__ blockSums, int n) {
    __shared__ int tmp[256];
    int gid = blockIdx.x * 256 + threadIdx.x;
    int v = (gid < n) ? in[gid] : 0;
    tmp[threadIdx.x] = v;
    __syncthreads();
    for (int off = 1; off < 256; off <<= 1) {
        int t = (threadIdx.x >= off) ? tmp[threadIdx.x - off] : 0;
        __syncthreads();
        tmp[threadIdx.x] += t;
        __syncthreads();
    }
    if (gid < n) out[gid] = tmp[threadIdx.x] - v;  // exclusive within chunk
    if (threadIdx.x == 255) blockSums[blockIdx.x] = tmp[255];
}

__global__ __launch_bounds__(1024) void scan_sums(int* __restrict__ bsums, int nb) {
    __shared__ int tmp[1024];
    int v = (threadIdx.x < nb) ? bsums[threadIdx.x] : 0;
    tmp[threadIdx.x] = v;
    __syncthreads();
    for (int off = 1; off < 1024; off <<= 1) {
        int t = (threadIdx.x >= off) ? tmp[threadIdx.x - off] : 0;
        __syncthreads();
        tmp[threadIdx.x] += t;
        __syncthreads();
    }
    if (threadIdx.x < nb) bsums[threadIdx.x] = tmp[threadIdx.x] - v;  // exclusive
}

__global__ __launch_bounds__(256) void part_scatter2(
    const int* __restrict__ src, const int* __restrict__ dst,
    const float* __restrict__ w, const int* __restrict__ offsT2,
    const int* __restrict__ bsums,
    int2* __restrict__ pkw, int2* __restrict__ skw,
    int E, int nb, int chunk, int hlen) {
    extern __shared__ int cur[];  // 2*nb ints
    int b = blockIdx.x;
    for (int i = threadIdx.x; i < nb; i += 256)
        cur[i] = offsT2[i * PBLK + b] + bsums[i];
    for (int i = threadIdx.x; i < nb; i += 256)
        cur[nb + i] = offsT2[hlen + i * PBLK + b] + bsums[nb + i] - E;
    __syncthreads();
    int beg = b * chunk, end = min(E, beg + chunk);
    for (int e = beg + threadIdx.x; e < end; e += 256) {
        int d = dst[e];
        int s = src[e];
        int wv = __float_as_int(w[e]);
        int kd = d >> BUCKET_SHIFT;
        int pos = atomicAdd(&cur[kd], 1);
        pkw[pos] = make_int2((int)((unsigned)s | ((unsigned)(d & 255) << 24)), wv);
        int ks = s >> BUCKET_SHIFT;
        int posS = atomicAdd(&cur[nb + ks], 1);
        skw[posS] = make_int2(s & 255, wv);
    }
}

__global__ __launch_bounds__(256) void bucket_sumS(
    const int2* __restrict__ skw, const int* __restrict__ offsT2,
    const int* __restrict__ bsums,
    float* __restrict__ deg_src, int E, int nb, int N, int hlen) {
    __shared__ float wsum[256];
    int k = blockIdx.x;
    int base = offsT2[hlen + k * PBLK] + bsums[nb + k] - E;
    int end = (k + 1 < nb) ? (offsT2[hlen + (k + 1) * PBLK] + bsums[nb + k + 1] - E) : E;
    int t = threadIdx.x;
    wsum[t] = 0.f;
    __syncthreads();
    for (int i = base + t; i < end; i += 256) {
        int2 v = skw[i];
        atomicAdd(&wsum[v.x], __int_as_float(v.y));
    }
    __syncthreads();
    int node = (k << BUCKET_SHIFT) + t;
    if (node < N) deg_src[node] = wsum[t];
}

__global__ __launch_bounds__(256) void bucket_build(
    const int2* __restrict__ pkw, const int* __restrict__ offsT,
    const int* __restrict__ bsums, const float* __restrict__ deg_src,
    int* __restrict__ row_start, int2* __restrict__ edata,
    int E, int nb, int N) {
    __shared__ int cnt[256];
    __shared__ float wsum[256];
    __shared__ int loc[256];
    __shared__ int cur2[256];
    extern __shared__ int2 stage[];  // DCAP int2

    int k = blockIdx.x;
    int base = offsT[k * PBLK] + bsums[k];
    int end = (k + 1 < nb) ? (offsT[(k + 1) * PBLK] + bsums[k + 1]) : E;
    int m = end - base;
    int t = threadIdx.x;
    cnt[t] = 0;
    wsum[t] = 0.f;
    __syncthreads();
    bool staged = (m <= DCAP);
    for (int i = t; i < m; i += 256) {
        int2 kw = pkw[base + i];
        if (staged) stage[i] = kw;
        int dl = (unsigned)kw.x >> 24;
        atomicAdd(&cnt[dl], 1);
        atomicAdd(&wsum[dl], __int_as_float(kw.y));
    }
    __syncthreads();
    int v = cnt[t];
    loc[t] = v;
    __syncthreads();
    for (int off = 1; off < 256; off <<= 1) {
        int tv = (t >= off) ? loc[t - off] : 0;
        __syncthreads();
        loc[t] += tv;
        __syncthreads();
    }
    int excl = loc[t] - v;
    loc[t] = excl;
    cur2[t] = 0;
    int node = (k << BUCKET_SHIFT) + t;
    if (node < N) row_start[node] = base + excl;
    if (k == 0 && t == 0) row_start[N] = E;
    __syncthreads();
    for (int i = t; i < m; i += 256) {
        int2 kw = staged ? stage[i] : pkw[base + i];
        int dl = (unsigned)kw.x >> 24;
        int s = kw.x & 0xFFFFFF;
        int pos = base + loc[dl] + atomicAdd(&cur2[dl], 1);
        float nw = __int_as_float(kw.y) * rsqrtf(deg_src[s] * wsum[dl]);
        edata[pos] = make_int2(s, __float_as_int(nw));
    }
}

// ---------------- MFMA GEMM ----------------

// W[l][k][n] f32 -> Wh/Wl bf16 in granule layout [(l*16+kc)*128+n][e], e=k&7.
__global__ __launch_bounds__(256) void prep_w(
    const float* __restrict__ W, unsigned short* __restrict__ Wh,
    unsigned short* __restrict__ Wl, int total) {
    int i = blockIdx.x * 256 + threadIdx.x;
    if (i >= total) return;
    int l = i >> 14;
    int rem = i & 16383;
    int k = rem >> 7, nn = rem & 127;
    float v = W[i];
    unsigned short h = bf16_rne(v);
    float fh = __uint_as_float((unsigned)h << 16);
    unsigned short lo = bf16_rne(v - fh);
    size_t oi = ((((size_t)l * 16 + (k >> 3)) * 128 + nn) << 3) + (k & 7);
    Wh[oi] = h;
    Wl[oi] = lo;
}

// Hb = bf16(A @ W): one 32-row tile per block; wave w owns cols [32w,32w+32).
// A(f32) split to hi/lo bf16 in LDS; W frags (hi/lo) held in registers.
__global__ __launch_bounds__(256) void gemm_mfma(
    const float* __restrict__ A, const unsigned short* __restrict__ Wh,
    const unsigned short* __restrict__ Wl, unsigned short* __restrict__ Hb,
    int n) {
    __shared__ s8v lds_hi[16][32];  // [kc][row^(kc&7)] granules of 8 bf16
    __shared__ s8v lds_lo[16][32];
    const int t = threadIdx.x;
    const int r0 = blockIdx.x * 32;
    const int l = t & 63;
    const int wv = t >> 6;          // wave = col stripe
    const int n0 = wv * 32;
    const int lr = l & 31, lh = l >> 5;

    // B fragments: bh/bl[k0] covers k in [16*k0, 16*k0+16), col n0+lr.
    s8v bh[8], bl[8];
#pragma unroll
    for (int k0 = 0; k0 < 8; ++k0) {
        int kc = k0 * 2 + lh;
        size_t gi = ((size_t)kc * 128 + n0 + lr) << 3;
        bh[k0] = *(const s8v*)(Wh + gi);
        bl[k0] = *(const s8v*)(Wl + gi);
    }

    // Stage A rows r0..r0+31: f32 -> (hi, lo) bf16 granules.
    {
        int row = t >> 3;       // 0..31
        int kc0 = t & 7;        // 0..7
        int r = r0 + row;
#pragma unroll
        for (int hhalf = 0; hhalf < 2; ++hhalf) {
            int kc = kc0 + 8 * hhalf;
            float4 v0 = make_float4(0.f, 0.f, 0.f, 0.f), v1 = v0;
            if (r < n) {
                const float4* ap = (const float4*)(A + (size_t)r * D128 + kc * 8);
                v0 = ap[0];
                v1 = ap[1];
            }
            s8v sh, sl;
#pragma unroll
            for (int e = 0; e < 8; ++e) {
                float v = (e < 4) ? ((const float*)&v0)[e] : ((const float*)&v1)[e - 4];
                unsigned short h = bf16_rne(v);
                float fh = __uint_as_float((unsigned)h << 16);
                sh[e] = (short)h;
                sl[e] = (short)bf16_rne(v - fh);
            }
            lds_hi[kc][row ^ (kc & 7)] = sh;
            lds_lo[kc][row ^ (kc & 7)] = sl;
        }
    }
    __syncthreads();

    f16v acc = {0.f, 0.f, 0.f, 0.f, 0.f, 0.f, 0.f, 0.f,
                0.f, 0.f, 0.f, 0.f, 0.f, 0.f, 0.f, 0.f};
#pragma unroll
    for (int k0 = 0; k0 < 8; ++k0) {
        int kc = k0 * 2 + lh;
        s8v ah = lds_hi[kc][lr ^ (kc & 7)];
        s8v al = lds_lo[kc][lr ^ (kc & 7)];
        acc = __builtin_amdgcn_mfma_f32_32x32x16_bf16(ah, bh[k0], acc, 0, 0, 0);
        acc = __builtin_amdgcn_mfma_f32_32x32x16_bf16(ah, bl[k0], acc, 0, 0, 0);
        acc = __builtin_amdgcn_mfma_f32_32x32x16_bf16(al, bh[k0], acc, 0, 0, 0);
    }

    // D mapping (verified): col = lane&31, row = (reg&3) + 8*(reg>>2) + 4*(lane>>5)
#pragma unroll
    for (int rg = 0; rg < 16; ++rg) {
        int grow = r0 + (rg & 3) + 8 * (rg >> 2) + 4 * lh;
        if (grow < n) Hb[(size_t)grow * D128 + n0 + lr] = bf16_rne(acc[rg]);
    }
}

// ---------------- aggregate (unchanged from R5) ----------------

__global__ __launch_bounds__(256) void aggregate_bf16(
    const unsigned short* __restrict__ hb, const int* __restrict__ rs,
    const int2* __restrict__ edata,
    const float* __restrict__ bias, float* __restrict__ out, int n) {
    int wave = threadIdx.x >> 6;
    int lane = threadIdx.x & 63;
    int node = blockIdx.x * 4 + wave;
    if (node >= n) return;
    int beg = rs[node], end = rs[node + 1];
    int half = lane >> 5, c = lane & 31;
    float4 a0 = make_float4(0.f, 0.f, 0.f, 0.f);
    float4 a1 = a0, a2 = a0, a3 = a0;
    int i = beg + half;
    for (; i + 6 < end; i += 8) {
        int2 e0 = edata[i];
        int2 e1 = edata[i + 2];
        int2 e2 = edata[i + 4];
        int2 e3 = edata[i + 6];
        uint2 p0 = ((const uint2*)(hb + (size_t)e0.x * D128))[c];
        uint2 p1 = ((const uint2*)(hb + (size_t)e1.x * D128))[c];
        uint2 p2 = ((const uint2*)(hb + (size_t)e2.x * D128))[c];
        uint2 p3 = ((const uint2*)(hb + (size_t)e3.x * D128))[c];
        float w0 = __int_as_float(e0.y), w1 = __int_as_float(e1.y);
        float w2 = __int_as_float(e2.y), w3 = __int_as_float(e3.y);
        a0.x = fmaf(__uint_as_float(p0.x << 16), w0, a0.x);
        a0.y = fmaf(__uint_as_float(p0.x & 0xffff0000u), w0, a0.y);
        a0.z = fmaf(__uint_as_float(p0.y << 16), w0, a0.z);
        a0.w = fmaf(__uint_as_float(p0.y & 0xffff0000u), w0, a0.w);
        a1.x = fmaf(__uint_as_float(p1.x << 16), w1, a1.x);
        a1.y = fmaf(__uint_as_float(p1.x & 0xffff0000u), w1, a1.y);
        a1.z = fmaf(__uint_as_float(p1.y << 16), w1, a1.z);
        a1.w = fmaf(__uint_as_float(p1.y & 0xffff0000u), w1, a1.w);
        a2.x = fmaf(__uint_as_float(p2.x << 16), w2, a2.x);
        a2.y = fmaf(__uint_as_float(p2.x & 0xffff0000u), w2, a2.y);
        a2.z = fmaf(__uint_as_float(p2.y << 16), w2, a2.z);
        a2.w = fmaf(__uint_as_float(p2.y & 0xffff0000u), w2, a2.w);
        a3.x = fmaf(__uint_as_float(p3.x << 16), w3, a3.x);
        a3.y = fmaf(__uint_as_float(p3.x & 0xffff0000u), w3, a3.y);
        a3.z = fmaf(__uint_as_float(p3.y << 16), w3, a3.z);
        a3.w = fmaf(__uint_as_float(p3.y & 0xffff0000u), w3, a3.w);
    }
    for (; i < end; i += 2) {
        int2 e0 = edata[i];
        uint2 p0 = ((const uint2*)(hb + (size_t)e0.x * D128))[c];
        float w0 = __int_as_float(e0.y);
        a0.x = fmaf(__uint_as_float(p0.x << 16), w0, a0.x);
        a0.y = fmaf(__uint_as_float(p0.x & 0xffff0000u), w0, a0.y);
        a0.z = fmaf(__uint_as_float(p0.y << 16), w0, a0.z);
        a0.w = fmaf(__uint_as_float(p0.y & 0xffff0000u), w0, a0.w);
    }
    a0.x += a1.x + a2.x + a3.x;
    a0.y += a1.y + a2.y + a3.y;
    a0.z += a1.z + a2.z + a3.z;
    a0.w += a1.w + a2.w + a3.w;
    a0.x += __shfl_xor(a0.x, 32);
    a0.y += __shfl_xor(a0.y, 32);
    a0.z += __shfl_xor(a0.z, 32);
    a0.w += __shfl_xor(a0.w, 32);
    if (half == 0) {
        float4 bb = ((const float4*)bias)[c];
        float4 o;
        o.x = elu1(a0.x + bb.x);
        o.y = elu1(a0.y + bb.y);
        o.z = elu1(a0.z + bb.z);
        o.w = elu1(a0.w + bb.w);
        ((float4*)(out + (size_t)node * D128))[c] = o;
    }
}

extern "C" void kernel_launch(void* const* d_in, const int* in_sizes, int n_in,
                              void* d_out, int out_size, void* d_ws, size_t ws_size,
                              hipStream_t stream) {
    const float* x   = (const float*)d_in[0];
    const float* ew  = (const float*)d_in[1];
    const float* W   = (const float*)d_in[2];
    const float* b   = (const float*)d_in[3];
    const int*   src = (const int*)d_in[4];
    const int*   dst = (const int*)d_in[5];
    float* out = (float*)d_out;

    const int N = in_sizes[0] / D128;
    const int E = in_sizes[1];
    const int L = in_sizes[2] / (D128 * D128);   // == 3 here
    const int nb = (N + 255) >> BUCKET_SHIFT;
    const int hlen = nb * PBLK;

    char* ws = (char*)d_ws;
    size_t off = 0;
    auto take = [&](size_t bytes) {
        void* p = ws + off;
        off = (off + bytes + 255) & ~(size_t)255;
        return p;
    };
    float* deg_src = (float*)take((size_t)N * 4);
    int*   histT2  = (int*)take((size_t)2 * hlen * 4);
    int*   offsT2  = (int*)take((size_t)2 * hlen * 4);
    int*   bsums   = (int*)take(1024 * 4);
    int*   rstart  = (int*)take((size_t)(N + 1) * 4);
    int2*  edata   = (int2*)take((size_t)E * 8);
    unsigned short* Hb = (unsigned short*)take((size_t)N * D128 * 2);
    unsigned short* Whg = (unsigned short*)take((size_t)L * D128 * D128 * 2);
    unsigned short* Wlg = (unsigned short*)take((size_t)L * D128 * D128 * 2);
    // partition scratch aliases Hb (dead before gemm0 writes Hb):
    // needs E*16 bytes <= N*256 bytes  (25.6MB == 25.6MB here)
    int2* pkw = (int2*)Hb;                     // E * 8
    int2* skw = ((int2*)Hb) + E;               // E * 8

    const int chunk = (E + PBLK - 1) / PBLK;
    const int sb2 = (2 * hlen + 255) / 256;    // == 2*nb <= 1024
    const size_t part_lds = (size_t)2 * nb * 4;
    const size_t dcap_lds = (size_t)DCAP * 8;

    const int wtotal = L * D128 * D128;
    prep_w<<<(wtotal + 255) / 256, 256, 0, stream>>>(W, Whg, Wlg, wtotal);

    part_hist2<<<PBLK, 256, part_lds, stream>>>(src, dst, histT2, E, nb, chunk, hlen);
    scan_block<<<sb2, 256, 0, stream>>>(histT2, offsT2, bsums, 2 * hlen);
    scan_sums<<<1, 1024, 0, stream>>>(bsums, sb2);
    part_scatter2<<<PBLK, 256, part_lds, stream>>>(src, dst, ew, offsT2, bsums,
                                                   pkw, skw, E, nb, chunk, hlen);
    bucket_sumS<<<nb, 256, 0, stream>>>(skw, offsT2, bsums, deg_src, E, nb, N, hlen);
    bucket_build<<<nb, 256, dcap_lds, stream>>>(pkw, offsT2, bsums, deg_src,
                                                rstart, edata, E, nb, N);

    const int gemm_grid = (N + 31) / 32;
    const int agg_grid = (N + 3) / 4;

    // layer i: A --mfma-gemm--> Hb (bf16) --agg(+b_i,ELU)--> out (f32)
    gemm_mfma<<<gemm_grid, 256, 0, stream>>>(x, Whg, Wlg, Hb, N);
    aggregate_bf16<<<agg_grid, 256, 0, stream>>>(Hb, rstart, edata, b, out, N);
    for (int l = 1; l < L; ++l) {
        gemm_mfma<<<gemm_grid, 256, 0, stream>>>(
            out, Whg + (size_t)l * D128 * D128, Wlg + (size_t)l * D128 * D128, Hb, N);
        aggregate_bf16<<<agg_grid, 256, 0, stream>>>(Hb, rstart, edata,
                                                     b + (size_t)l * D128, out, N);
    }
}

// Round 8
// 360.830 us; speedup vs baseline: 1.7652x; 1.0108x over previous
//
#include <hip/hip_runtime.h>
#include <hip/hip_bf16.h>

// HeteroGCNConv: 3-layer GCN, N=100000, E=1600000, D=128, f32.
// R7: bf16 activation chain — agg0/1 write bf16 table Ab (half write traffic);
//     gemm1/2 take bf16 A (no A-split: 2 MFMA/k-chunk, 64-row tiles, half
//     W-frag re-reads). agg2 writes f32 d_out. absmax budget: 5 bf16 quant
//     events ~1.5-2e-3 < 3.28e-3 threshold.

#define D128 128
#define PBLK 256          // partition blocks; MUST equal 256 (scan-fold trick)
#define BUCKET_SHIFT 8
#define DCAP 7168         // staged edges per bucket in pass D (57KB LDS)

typedef __attribute__((ext_vector_type(8))) short s8v;     // 8 bf16 = 4 VGPR
typedef __attribute__((ext_vector_type(16))) float f16v;   // 16 f32 acc

__device__ __forceinline__ float elu1(float x) {
    return x > 0.f ? x : (expf(x) - 1.f);
}

__device__ __forceinline__ unsigned short bf16_rne(float v) {
    unsigned u = __float_as_uint(v);
    return (unsigned short)((u + 0x7fffu + ((u >> 16) & 1u)) >> 16);
}

// ---------------- build chain ----------------

__global__ __launch_bounds__(256) void part_hist2(
    const int* __restrict__ src, const int* __restrict__ dst,
    int* __restrict__ histT2, int E, int nb, int chunk, int hlen) {
    extern __shared__ int sh[];  // 2*nb ints
    for (int i = threadIdx.x; i < 2 * nb; i += 256) sh[i] = 0;
    __syncthreads();
    int b = blockIdx.x;
    int beg = b * chunk, end = min(E, beg + chunk);
    for (int e = beg + threadIdx.x; e < end; e += 256) {
        atomicAdd(&sh[dst[e] >> BUCKET_SHIFT], 1);
        atomicAdd(&sh[nb + (src[e] >> BUCKET_SHIFT)], 1);
    }
    __syncthreads();
    for (int i = threadIdx.x; i < nb; i += 256)
        histT2[i * PBLK + b] = sh[i];
    for (int i = threadIdx.x; i < nb; i += 256)
        histT2[hlen + i * PBLK + b] = sh[nb + i];
}

// In-place per-256-chunk exclusive scan; chunk sums to blockSums.
__global__ __launch_bounds__(256) void scan_block(
    int* __restrict__ data, int* __restrict__ blockSums, int n) {
    __shared__ int tmp[256];
    int gid = blockIdx.x * 256 + threadIdx.x;
    int v = (gid < n) ? data[gid] : 0;
    tmp[threadIdx.x] = v;
    __syncthreads();
    for (int off = 1; off < 256; off <<= 1) {
        int t = (threadIdx.x >= off) ? tmp[threadIdx.x - off] : 0;
        __syncthreads();
        tmp[threadIdx.x] += t;
        __syncthreads();
    }
    if (gid < n) data[gid] = tmp[threadIdx.x] - v;  // exclusive within chunk
    if (threadIdx.x == 255) blockSums[blockIdx.x] = tmp[255];
}

__global__ __launch_bounds__(1024) void scan_sums(int* __restrict__ bsums, int nb) {
    __shared__ int tmp[1024];
    int v = (threadIdx.x < nb) ? bsums[threadIdx.x] : 0;
    tmp[threadIdx.x] = v;
    __syncthreads();
    for (int off = 1; off < 1024; off <<= 1) {
        int t = (threadIdx.x >= off) ? tmp[threadIdx.x - off] : 0;
        __syncthreads();
        tmp[threadIdx.x] += t;
        __syncthreads();
    }
    if (threadIdx.x < nb) bsums[threadIdx.x] = tmp[threadIdx.x] - v;  // exclusive
}

__global__ __launch_bounds__(256) void part_scatter2(
    const int* __restrict__ src, const int* __restrict__ dst,
    const float* __restrict__ w, const int* __restrict__ offsT2,
    const int* __restrict__ bsums,
    int2* __restrict__ pkw, int2* __restrict__ skw,
    int E, int nb, int chunk, int hlen) {
    extern __shared__ int cur[];  // 2*nb ints
    int b = blockIdx.x;
    for (int i = threadIdx.x; i < nb; i += 256)
        cur[i] = offsT2[i * PBLK + b] + bsums[i];
    for (int i = threadIdx.x; i < nb; i += 256)
        cur[nb + i] = offsT2[hlen + i * PBLK + b] + bsums[nb + i] - E;
    __syncthreads();
    int beg = b * chunk, end = min(E, beg + chunk);
    for (int e = beg + threadIdx.x; e < end; e += 256) {
        int d = dst[e];
        int s = src[e];
        int wv = __float_as_int(w[e]);
        int kd = d >> BUCKET_SHIFT;
        int pos = atomicAdd(&cur[kd], 1);
        pkw[pos] = make_int2((int)((unsigned)s | ((unsigned)(d & 255) << 24)), wv);
        int ks = s >> BUCKET_SHIFT;
        int posS = atomicAdd(&cur[nb + ks], 1);
        skw[posS] = make_int2(s & 255, wv);
    }
}

__global__ __launch_bounds__(256) void bucket_sumS(
    const int2* __restrict__ skw, const int* __restrict__ offsT2,
    const int* __restrict__ bsums,
    float* __restrict__ deg_src, int E, int nb, int N, int hlen) {
    __shared__ float wsum[256];
    int k = blockIdx.x;
    int base = offsT2[hlen + k * PBLK] + bsums[nb + k] - E;
    int end = (k + 1 < nb) ? (offsT2[hlen + (k + 1) * PBLK] + bsums[nb + k + 1] - E) : E;
    int t = threadIdx.x;
    wsum[t] = 0.f;
    __syncthreads();
    for (int i = base + t; i < end; i += 256) {
        int2 v = skw[i];
        atomicAdd(&wsum[v.x], __int_as_float(v.y));
    }
    __syncthreads();
    int node = (k << BUCKET_SHIFT) + t;
    if (node < N) deg_src[node] = wsum[t];
}

__global__ __launch_bounds__(256) void bucket_build(
    const int2* __restrict__ pkw, const int* __restrict__ offsT,
    const int* __restrict__ bsums, const float* __restrict__ deg_src,
    int* __restrict__ row_start, int2* __restrict__ edata,
    int E, int nb, int N) {
    __shared__ int cnt[256];
    __shared__ float wsum[256];
    __shared__ int loc[256];
    __shared__ int cur2[256];
    extern __shared__ int2 stage[];  // DCAP int2

    int k = blockIdx.x;
    int base = offsT[k * PBLK] + bsums[k];
    int end = (k + 1 < nb) ? (offsT[(k + 1) * PBLK] + bsums[k + 1]) : E;
    int m = end - base;
    int t = threadIdx.x;
    cnt[t] = 0;
    wsum[t] = 0.f;
    __syncthreads();
    bool staged = (m <= DCAP);
    for (int i = t; i < m; i += 256) {
        int2 kw = pkw[base + i];
        if (staged) stage[i] = kw;
        int dl = (unsigned)kw.x >> 24;
        atomicAdd(&cnt[dl], 1);
        atomicAdd(&wsum[dl], __int_as_float(kw.y));
    }
    __syncthreads();
    int v = cnt[t];
    loc[t] = v;
    __syncthreads();
    for (int off = 1; off < 256; off <<= 1) {
        int tv = (t >= off) ? loc[t - off] : 0;
        __syncthreads();
        loc[t] += tv;
        __syncthreads();
    }
    int excl = loc[t] - v;
    loc[t] = excl;
    cur2[t] = 0;
    int node = (k << BUCKET_SHIFT) + t;
    if (node < N) row_start[node] = base + excl;
    if (k == 0 && t == 0) row_start[N] = E;
    __syncthreads();
    for (int i = t; i < m; i += 256) {
        int2 kw = staged ? stage[i] : pkw[base + i];
        int dl = (unsigned)kw.x >> 24;
        int s = kw.x & 0xFFFFFF;
        int pos = base + loc[dl] + atomicAdd(&cur2[dl], 1);
        float nw = __int_as_float(kw.y) * rsqrtf(deg_src[s] * wsum[dl]);
        edata[pos] = make_int2(s, __float_as_int(nw));
    }
}

// ---------------- MFMA GEMM ----------------

// W[l][k][n] f32 -> Wh/Wl bf16 in granule layout [(l*16+kc)*128+n][e], e=k&7.
__global__ __launch_bounds__(256) void prep_w(
    const float* __restrict__ W, unsigned short* __restrict__ Wh,
    unsigned short* __restrict__ Wl, int total) {
    int i = blockIdx.x * 256 + threadIdx.x;
    if (i >= total) return;
    int l = i >> 14;
    int rem = i & 16383;
    int k = rem >> 7, nn = rem & 127;
    float v = W[i];
    unsigned short h = bf16_rne(v);
    float fh = __uint_as_float((unsigned)h << 16);
    unsigned short lo = bf16_rne(v - fh);
    size_t oi = ((((size_t)l * 16 + (k >> 3)) * 128 + nn) << 3) + (k & 7);
    Wh[oi] = h;
    Wl[oi] = lo;
}

// Layer 0: A f32, hi/lo split, 32-row tiles, 3 MFMA/k-chunk.
__global__ __launch_bounds__(256) void gemm_mfma_f32(
    const float* __restrict__ A, const unsigned short* __restrict__ Wh,
    const unsigned short* __restrict__ Wl, unsigned short* __restrict__ Hb,
    int n) {
    __shared__ s8v lds_hi[16][32];  // [kc][row^(kc&7)]
    __shared__ s8v lds_lo[16][32];
    const int t = threadIdx.x;
    const int r0 = blockIdx.x * 32;
    const int l = t & 63;
    const int wv = t >> 6;
    const int n0 = wv * 32;
    const int lr = l & 31, lh = l >> 5;

    s8v bh[8], bl[8];
#pragma unroll
    for (int k0 = 0; k0 < 8; ++k0) {
        int kc = k0 * 2 + lh;
        size_t gi = ((size_t)kc * 128 + n0 + lr) << 3;
        bh[k0] = *(const s8v*)(Wh + gi);
        bl[k0] = *(const s8v*)(Wl + gi);
    }

    {
        int row = t >> 3;
        int kc0 = t & 7;
        int r = r0 + row;
#pragma unroll
        for (int hhalf = 0; hhalf < 2; ++hhalf) {
            int kc = kc0 + 8 * hhalf;
            float4 v0 = make_float4(0.f, 0.f, 0.f, 0.f), v1 = v0;
            if (r < n) {
                const float4* ap = (const float4*)(A + (size_t)r * D128 + kc * 8);
                v0 = ap[0];
                v1 = ap[1];
            }
            s8v sh, sl;
#pragma unroll
            for (int e = 0; e < 8; ++e) {
                float v = (e < 4) ? ((const float*)&v0)[e] : ((const float*)&v1)[e - 4];
                unsigned short h = bf16_rne(v);
                float fh = __uint_as_float((unsigned)h << 16);
                sh[e] = (short)h;
                sl[e] = (short)bf16_rne(v - fh);
            }
            lds_hi[kc][row ^ (kc & 7)] = sh;
            lds_lo[kc][row ^ (kc & 7)] = sl;
        }
    }
    __syncthreads();

    f16v acc = {0.f, 0.f, 0.f, 0.f, 0.f, 0.f, 0.f, 0.f,
                0.f, 0.f, 0.f, 0.f, 0.f, 0.f, 0.f, 0.f};
#pragma unroll
    for (int k0 = 0; k0 < 8; ++k0) {
        int kc = k0 * 2 + lh;
        s8v ah = lds_hi[kc][lr ^ (kc & 7)];
        s8v al = lds_lo[kc][lr ^ (kc & 7)];
        acc = __builtin_amdgcn_mfma_f32_32x32x16_bf16(ah, bh[k0], acc, 0, 0, 0);
        acc = __builtin_amdgcn_mfma_f32_32x32x16_bf16(ah, bl[k0], acc, 0, 0, 0);
        acc = __builtin_amdgcn_mfma_f32_32x32x16_bf16(al, bh[k0], acc, 0, 0, 0);
    }

#pragma unroll
    for (int rg = 0; rg < 16; ++rg) {
        int grow = r0 + (rg & 3) + 8 * (rg >> 2) + 4 * lh;
        if (grow < n) Hb[(size_t)grow * D128 + n0 + lr] = bf16_rne(acc[rg]);
    }
}

// Layers 1+: A bf16 (exact), 64-row tiles, 2 MFMA/k-chunk.
__global__ __launch_bounds__(256) void gemm_mfma_bf16(
    const unsigned short* __restrict__ A, const unsigned short* __restrict__ Wh,
    const unsigned short* __restrict__ Wl, unsigned short* __restrict__ Hb,
    int n) {
    __shared__ s8v lds_a[16][64];   // [kc][row^(kc&7)]
    const int t = threadIdx.x;
    const int r0 = blockIdx.x * 64;
    const int l = t & 63;
    const int wv = t >> 6;
    const int n0 = wv * 32;
    const int lr = l & 31, lh = l >> 5;

    s8v bh[8], bl[8];
#pragma unroll
    for (int k0 = 0; k0 < 8; ++k0) {
        int kc = k0 * 2 + lh;
        size_t gi = ((size_t)kc * 128 + n0 + lr) << 3;
        bh[k0] = *(const s8v*)(Wh + gi);
        bl[k0] = *(const s8v*)(Wl + gi);
    }

    // Stage 64 rows x 128 bf16: 1024 granules of 16B, 4 per thread.
#pragma unroll
    for (int g4 = 0; g4 < 4; ++g4) {
        int g = t * 4 + g4;
        int row = g >> 4, kc = g & 15;
        int r = r0 + row;
        s8v v = {0, 0, 0, 0, 0, 0, 0, 0};
        if (r < n) v = *(const s8v*)(A + (size_t)r * D128 + kc * 8);
        lds_a[kc][row ^ (kc & 7)] = v;
    }
    __syncthreads();

    f16v acc0 = {0.f, 0.f, 0.f, 0.f, 0.f, 0.f, 0.f, 0.f,
                 0.f, 0.f, 0.f, 0.f, 0.f, 0.f, 0.f, 0.f};
    f16v acc1 = acc0;
#pragma unroll
    for (int k0 = 0; k0 < 8; ++k0) {
        int kc = k0 * 2 + lh;
        s8v a0 = lds_a[kc][lr ^ (kc & 7)];
        s8v a1 = lds_a[kc][(32 + lr) ^ (kc & 7)];
        acc0 = __builtin_amdgcn_mfma_f32_32x32x16_bf16(a0, bh[k0], acc0, 0, 0, 0);
        acc0 = __builtin_amdgcn_mfma_f32_32x32x16_bf16(a0, bl[k0], acc0, 0, 0, 0);
        acc1 = __builtin_amdgcn_mfma_f32_32x32x16_bf16(a1, bh[k0], acc1, 0, 0, 0);
        acc1 = __builtin_amdgcn_mfma_f32_32x32x16_bf16(a1, bl[k0], acc1, 0, 0, 0);
    }

#pragma unroll
    for (int rg = 0; rg < 16; ++rg) {
        int rr = (rg & 3) + 8 * (rg >> 2) + 4 * lh;
        int grow0 = r0 + rr;
        int grow1 = r0 + 32 + rr;
        if (grow0 < n) Hb[(size_t)grow0 * D128 + n0 + lr] = bf16_rne(acc0[rg]);
        if (grow1 < n) Hb[(size_t)grow1 * D128 + n0 + lr] = bf16_rne(acc1[rg]);
    }
}

// ---------------- aggregate ----------------

// One wave per dst node; gathers bf16 rows, f32 accum; writes bf16 table
// (obf=1, to Ab) or f32 (obf=0, to outf).
__global__ __launch_bounds__(256) void aggregate_bf16(
    const unsigned short* __restrict__ hb, const int* __restrict__ rs,
    const int2* __restrict__ edata, const float* __restrict__ bias,
    unsigned short* __restrict__ outb, float* __restrict__ outf,
    int obf, int n) {
    int wave = threadIdx.x >> 6;
    int lane = threadIdx.x & 63;
    int node = blockIdx.x * 4 + wave;
    if (node >= n) return;
    int beg = rs[node], end = rs[node + 1];
    int half = lane >> 5, c = lane & 31;
    float4 a0 = make_float4(0.f, 0.f, 0.f, 0.f);
    float4 a1 = a0, a2 = a0, a3 = a0;
    int i = beg + half;
    for (; i + 6 < end; i += 8) {
        int2 e0 = edata[i];
        int2 e1 = edata[i + 2];
        int2 e2 = edata[i + 4];
        int2 e3 = edata[i + 6];
        uint2 p0 = ((const uint2*)(hb + (size_t)e0.x * D128))[c];
        uint2 p1 = ((const uint2*)(hb + (size_t)e1.x * D128))[c];
        uint2 p2 = ((const uint2*)(hb + (size_t)e2.x * D128))[c];
        uint2 p3 = ((const uint2*)(hb + (size_t)e3.x * D128))[c];
        float w0 = __int_as_float(e0.y), w1 = __int_as_float(e1.y);
        float w2 = __int_as_float(e2.y), w3 = __int_as_float(e3.y);
        a0.x = fmaf(__uint_as_float(p0.x << 16), w0, a0.x);
        a0.y = fmaf(__uint_as_float(p0.x & 0xffff0000u), w0, a0.y);
        a0.z = fmaf(__uint_as_float(p0.y << 16), w0, a0.z);
        a0.w = fmaf(__uint_as_float(p0.y & 0xffff0000u), w0, a0.w);
        a1.x = fmaf(__uint_as_float(p1.x << 16), w1, a1.x);
        a1.y = fmaf(__uint_as_float(p1.x & 0xffff0000u), w1, a1.y);
        a1.z = fmaf(__uint_as_float(p1.y << 16), w1, a1.z);
        a1.w = fmaf(__uint_as_float(p1.y & 0xffff0000u), w1, a1.w);
        a2.x = fmaf(__uint_as_float(p2.x << 16), w2, a2.x);
        a2.y = fmaf(__uint_as_float(p2.x & 0xffff0000u), w2, a2.y);
        a2.z = fmaf(__uint_as_float(p2.y << 16), w2, a2.z);
        a2.w = fmaf(__uint_as_float(p2.y & 0xffff0000u), w2, a2.w);
        a3.x = fmaf(__uint_as_float(p3.x << 16), w3, a3.x);
        a3.y = fmaf(__uint_as_float(p3.x & 0xffff0000u), w3, a3.y);
        a3.z = fmaf(__uint_as_float(p3.y << 16), w3, a3.z);
        a3.w = fmaf(__uint_as_float(p3.y & 0xffff0000u), w3, a3.w);
    }
    for (; i < end; i += 2) {
        int2 e0 = edata[i];
        uint2 p0 = ((const uint2*)(hb + (size_t)e0.x * D128))[c];
        float w0 = __int_as_float(e0.y);
        a0.x = fmaf(__uint_as_float(p0.x << 16), w0, a0.x);
        a0.y = fmaf(__uint_as_float(p0.x & 0xffff0000u), w0, a0.y);
        a0.z = fmaf(__uint_as_float(p0.y << 16), w0, a0.z);
        a0.w = fmaf(__uint_as_float(p0.y & 0xffff0000u), w0, a0.w);
    }
    a0.x += a1.x + a2.x + a3.x;
    a0.y += a1.y + a2.y + a3.y;
    a0.z += a1.z + a2.z + a3.z;
    a0.w += a1.w + a2.w + a3.w;
    a0.x += __shfl_xor(a0.x, 32);
    a0.y += __shfl_xor(a0.y, 32);
    a0.z += __shfl_xor(a0.z, 32);
    a0.w += __shfl_xor(a0.w, 32);
    if (half == 0) {
        float4 bb = ((const float4*)bias)[c];
        float4 o;
        o.x = elu1(a0.x + bb.x);
        o.y = elu1(a0.y + bb.y);
        o.z = elu1(a0.z + bb.z);
        o.w = elu1(a0.w + bb.w);
        if (obf) {
            uint2 p;
            p.x = (unsigned)bf16_rne(o.x) | ((unsigned)bf16_rne(o.y) << 16);
            p.y = (unsigned)bf16_rne(o.z) | ((unsigned)bf16_rne(o.w) << 16);
            ((uint2*)(outb + (size_t)node * D128))[c] = p;
        } else {
            ((float4*)(outf + (size_t)node * D128))[c] = o;
        }
    }
}

extern "C" void kernel_launch(void* const* d_in, const int* in_sizes, int n_in,
                              void* d_out, int out_size, void* d_ws, size_t ws_size,
                              hipStream_t stream) {
    const float* x   = (const float*)d_in[0];
    const float* ew  = (const float*)d_in[1];
    const float* W   = (const float*)d_in[2];
    const float* b   = (const float*)d_in[3];
    const int*   src = (const int*)d_in[4];
    const int*   dst = (const int*)d_in[5];
    float* out = (float*)d_out;

    const int N = in_sizes[0] / D128;
    const int E = in_sizes[1];
    const int L = in_sizes[2] / (D128 * D128);   // == 3 here
    const int nb = (N + 255) >> BUCKET_SHIFT;
    const int hlen = nb * PBLK;

    char* ws = (char*)d_ws;
    size_t off = 0;
    auto take = [&](size_t bytes) {
        void* p = ws + off;
        off = (off + bytes + 255) & ~(size_t)255;
        return p;
    };
    float* deg_src = (float*)take((size_t)N * 4);
    int*   histT2  = (int*)take((size_t)2 * hlen * 4);  // scanned in-place
    int*   bsums   = (int*)take(1024 * 4);
    int*   rstart  = (int*)take((size_t)(N + 1) * 4);
    int2*  edata   = (int2*)take((size_t)E * 8);
    unsigned short* Hb = (unsigned short*)take((size_t)N * D128 * 2);
    unsigned short* Ab = (unsigned short*)take((size_t)N * D128 * 2);
    unsigned short* Whg = (unsigned short*)take((size_t)L * D128 * D128 * 2);
    unsigned short* Wlg = (unsigned short*)take((size_t)L * D128 * D128 * 2);
    // partition scratch aliases Ab (dead before agg0 writes Ab):
    // needs E*16 bytes <= N*256 bytes  (25.6MB == 25.6MB here)
    int2* pkw = (int2*)Ab;                     // E * 8
    int2* skw = ((int2*)Ab) + E;               // E * 8

    const int chunk = (E + PBLK - 1) / PBLK;
    const int sb2 = (2 * hlen + 255) / 256;    // == 2*nb <= 1024
    const size_t part_lds = (size_t)2 * nb * 4;
    const size_t dcap_lds = (size_t)DCAP * 8;

    const int wtotal = L * D128 * D128;
    prep_w<<<(wtotal + 255) / 256, 256, 0, stream>>>(W, Whg, Wlg, wtotal);

    part_hist2<<<PBLK, 256, part_lds, stream>>>(src, dst, histT2, E, nb, chunk, hlen);
    scan_block<<<sb2, 256, 0, stream>>>(histT2, bsums, 2 * hlen);
    scan_sums<<<1, 1024, 0, stream>>>(bsums, sb2);
    part_scatter2<<<PBLK, 256, part_lds, stream>>>(src, dst, ew, histT2, bsums,
                                                   pkw, skw, E, nb, chunk, hlen);
    bucket_sumS<<<nb, 256, 0, stream>>>(skw, histT2, bsums, deg_src, E, nb, N, hlen);
    bucket_build<<<nb, 256, dcap_lds, stream>>>(pkw, histT2, bsums, deg_src,
                                                rstart, edata, E, nb, N);

    const int g32 = (N + 31) / 32;
    const int g64 = (N + 63) / 64;
    const int agg_grid = (N + 3) / 4;

    // layer 0: x(f32) --mfma--> Hb ; agg(+b0,ELU) --> Ab (bf16)
    gemm_mfma_f32<<<g32, 256, 0, stream>>>(x, Whg, Wlg, Hb, N);
    aggregate_bf16<<<agg_grid, 256, 0, stream>>>(Hb, rstart, edata, b,
                                                 Ab, nullptr, 1, N);
    // layer 1: Ab --mfma--> Hb ; agg(+b1,ELU) --> Ab
    gemm_mfma_bf16<<<g64, 256, 0, stream>>>(Ab, Whg + D128 * D128,
                                            Wlg + D128 * D128, Hb, N);
    aggregate_bf16<<<agg_grid, 256, 0, stream>>>(Hb, rstart, edata, b + D128,
                                                 Ab, nullptr, 1, N);
    // layer 2: Ab --mfma--> Hb ; agg(+b2,ELU) --> d_out (f32)
    gemm_mfma_bf16<<<g64, 256, 0, stream>>>(Ab, Whg + 2 * D128 * D128,
                                            Wlg + 2 * D128 * D128, Hb, N);
    aggregate_bf16<<<agg_grid, 256, 0, stream>>>(Hb, rstart, edata, b + 2 * D128,
                                                 nullptr, out, 0, N);
}

// Round 9
// 350.876 us; speedup vs baseline: 1.8153x; 1.0284x over previous
//
#include <hip/hip_runtime.h>
#include <hip/hip_bf16.h>

// HeteroGCNConv: 3-layer GCN, N=100000, E=1600000, D=128, f32.
// R8: aggregate rewrite — edata stores (src<<8 byte-offset, nw) so gather addr
//     is SGPR-base + 1 v_add; uint4 gathers with 16 lanes/row = 4 edges/vmem
//     instr, x2 unroll; shfl reduce over 4 edge-groups. Persistent GEMM blocks
//     (W frags loaded once per block). Build chain unchanged.

#define D128 128
#define PBLK 256          // partition blocks; MUST equal 256 (scan-fold trick)
#define BUCKET_SHIFT 8
#define DCAP 7168         // staged edges per bucket in pass D (57KB LDS)

typedef __attribute__((ext_vector_type(8))) short s8v;     // 8 bf16 = 4 VGPR
typedef __attribute__((ext_vector_type(16))) float f16v;   // 16 f32 acc

__device__ __forceinline__ float elu1(float x) {
    return x > 0.f ? x : (expf(x) - 1.f);
}

__device__ __forceinline__ unsigned short bf16_rne(float v) {
    unsigned u = __float_as_uint(v);
    return (unsigned short)((u + 0x7fffu + ((u >> 16) & 1u)) >> 16);
}

// ---------------- build chain ----------------

__global__ __launch_bounds__(256) void part_hist2(
    const int* __restrict__ src, const int* __restrict__ dst,
    int* __restrict__ histT2, int E, int nb, int chunk, int hlen) {
    extern __shared__ int sh[];  // 2*nb ints
    for (int i = threadIdx.x; i < 2 * nb; i += 256) sh[i] = 0;
    __syncthreads();
    int b = blockIdx.x;
    int beg = b * chunk, end = min(E, beg + chunk);
    for (int e = beg + threadIdx.x; e < end; e += 256) {
        atomicAdd(&sh[dst[e] >> BUCKET_SHIFT], 1);
        atomicAdd(&sh[nb + (src[e] >> BUCKET_SHIFT)], 1);
    }
    __syncthreads();
    for (int i = threadIdx.x; i < nb; i += 256)
        histT2[i * PBLK + b] = sh[i];
    for (int i = threadIdx.x; i < nb; i += 256)
        histT2[hlen + i * PBLK + b] = sh[nb + i];
}

// In-place per-256-chunk exclusive scan; chunk sums to blockSums.
__global__ __launch_bounds__(256) void scan_block(
    int* __restrict__ data, int* __restrict__ blockSums, int n) {
    __shared__ int tmp[256];
    int gid = blockIdx.x * 256 + threadIdx.x;
    int v = (gid < n) ? data[gid] : 0;
    tmp[threadIdx.x] = v;
    __syncthreads();
    for (int off = 1; off < 256; off <<= 1) {
        int t = (threadIdx.x >= off) ? tmp[threadIdx.x - off] : 0;
        __syncthreads();
        tmp[threadIdx.x] += t;
        __syncthreads();
    }
    if (gid < n) data[gid] = tmp[threadIdx.x] - v;  // exclusive within chunk
    if (threadIdx.x == 255) blockSums[blockIdx.x] = tmp[255];
}

__global__ __launch_bounds__(1024) void scan_sums(int* __restrict__ bsums, int nb) {
    __shared__ int tmp[1024];
    int v = (threadIdx.x < nb) ? bsums[threadIdx.x] : 0;
    tmp[threadIdx.x] = v;
    __syncthreads();
    for (int off = 1; off < 1024; off <<= 1) {
        int t = (threadIdx.x >= off) ? tmp[threadIdx.x - off] : 0;
        __syncthreads();
        tmp[threadIdx.x] += t;
        __syncthreads();
    }
    if (threadIdx.x < nb) bsums[threadIdx.x] = tmp[threadIdx.x] - v;  // exclusive
}

__global__ __launch_bounds__(256) void part_scatter2(
    const int* __restrict__ src, const int* __restrict__ dst,
    const float* __restrict__ w, const int* __restrict__ offsT2,
    const int* __restrict__ bsums,
    int2* __restrict__ pkw, int2* __restrict__ skw,
    int E, int nb, int chunk, int hlen) {
    extern __shared__ int cur[];  // 2*nb ints
    int b = blockIdx.x;
    for (int i = threadIdx.x; i < nb; i += 256)
        cur[i] = offsT2[i * PBLK + b] + bsums[i];
    for (int i = threadIdx.x; i < nb; i += 256)
        cur[nb + i] = offsT2[hlen + i * PBLK + b] + bsums[nb + i] - E;
    __syncthreads();
    int beg = b * chunk, end = min(E, beg + chunk);
    for (int e = beg + threadIdx.x; e < end; e += 256) {
        int d = dst[e];
        int s = src[e];
        int wv = __float_as_int(w[e]);
        int kd = d >> BUCKET_SHIFT;
        int pos = atomicAdd(&cur[kd], 1);
        pkw[pos] = make_int2((int)((unsigned)s | ((unsigned)(d & 255) << 24)), wv);
        int ks = s >> BUCKET_SHIFT;
        int posS = atomicAdd(&cur[nb + ks], 1);
        skw[posS] = make_int2(s & 255, wv);
    }
}

__global__ __launch_bounds__(256) void bucket_sumS(
    const int2* __restrict__ skw, const int* __restrict__ offsT2,
    const int* __restrict__ bsums,
    float* __restrict__ deg_src, int E, int nb, int N, int hlen) {
    __shared__ float wsum[256];
    int k = blockIdx.x;
    int base = offsT2[hlen + k * PBLK] + bsums[nb + k] - E;
    int end = (k + 1 < nb) ? (offsT2[hlen + (k + 1) * PBLK] + bsums[nb + k + 1] - E) : E;
    int t = threadIdx.x;
    wsum[t] = 0.f;
    __syncthreads();
    for (int i = base + t; i < end; i += 256) {
        int2 v = skw[i];
        atomicAdd(&wsum[v.x], __int_as_float(v.y));
    }
    __syncthreads();
    int node = (k << BUCKET_SHIFT) + t;
    if (node < N) deg_src[node] = wsum[t];
}

// edata stores (src<<8 = byte offset into bf16 table, nw f32).
__global__ __launch_bounds__(256) void bucket_build(
    const int2* __restrict__ pkw, const int* __restrict__ offsT,
    const int* __restrict__ bsums, const float* __restrict__ deg_src,
    int* __restrict__ row_start, int2* __restrict__ edata,
    int E, int nb, int N) {
    __shared__ int cnt[256];
    __shared__ float wsum[256];
    __shared__ int loc[256];
    __shared__ int cur2[256];
    extern __shared__ int2 stage[];  // DCAP int2

    int k = blockIdx.x;
    int base = offsT[k * PBLK] + bsums[k];
    int end = (k + 1 < nb) ? (offsT[(k + 1) * PBLK] + bsums[k + 1]) : E;
    int m = end - base;
    int t = threadIdx.x;
    cnt[t] = 0;
    wsum[t] = 0.f;
    __syncthreads();
    bool staged = (m <= DCAP);
    for (int i = t; i < m; i += 256) {
        int2 kw = pkw[base + i];
        if (staged) stage[i] = kw;
        int dl = (unsigned)kw.x >> 24;
        atomicAdd(&cnt[dl], 1);
        atomicAdd(&wsum[dl], __int_as_float(kw.y));
    }
    __syncthreads();
    int v = cnt[t];
    loc[t] = v;
    __syncthreads();
    for (int off = 1; off < 256; off <<= 1) {
        int tv = (t >= off) ? loc[t - off] : 0;
        __syncthreads();
        loc[t] += tv;
        __syncthreads();
    }
    int excl = loc[t] - v;
    loc[t] = excl;
    cur2[t] = 0;
    int node = (k << BUCKET_SHIFT) + t;
    if (node < N) row_start[node] = base + excl;
    if (k == 0 && t == 0) row_start[N] = E;
    __syncthreads();
    for (int i = t; i < m; i += 256) {
        int2 kw = staged ? stage[i] : pkw[base + i];
        int dl = (unsigned)kw.x >> 24;
        int s = kw.x & 0xFFFFFF;
        int pos = base + loc[dl] + atomicAdd(&cur2[dl], 1);
        float nw = __int_as_float(kw.y) * rsqrtf(deg_src[s] * wsum[dl]);
        edata[pos] = make_int2(s << 8, __float_as_int(nw));
    }
}

// ---------------- MFMA GEMM ----------------

// W[l][k][n] f32 -> Wh/Wl bf16 in granule layout [(l*16+kc)*128+n][e], e=k&7.
__global__ __launch_bounds__(256) void prep_w(
    const float* __restrict__ W, unsigned short* __restrict__ Wh,
    unsigned short* __restrict__ Wl, int total) {
    int i = blockIdx.x * 256 + threadIdx.x;
    if (i >= total) return;
    int l = i >> 14;
    int rem = i & 16383;
    int k = rem >> 7, nn = rem & 127;
    float v = W[i];
    unsigned short h = bf16_rne(v);
    float fh = __uint_as_float((unsigned)h << 16);
    unsigned short lo = bf16_rne(v - fh);
    size_t oi = ((((size_t)l * 16 + (k >> 3)) * 128 + nn) << 3) + (k & 7);
    Wh[oi] = h;
    Wl[oi] = lo;
}

// Layer 0: A f32, hi/lo split, 32-row tiles, persistent blocks.
__global__ __launch_bounds__(256) void gemm_mfma_f32(
    const float* __restrict__ A, const unsigned short* __restrict__ Wh,
    const unsigned short* __restrict__ Wl, unsigned short* __restrict__ Hb,
    int n, int nblk) {
    __shared__ s8v lds_hi[16][32];  // [kc][row^(kc&7)]
    __shared__ s8v lds_lo[16][32];
    const int t = threadIdx.x;
    const int l = t & 63;
    const int wv = t >> 6;
    const int n0 = wv * 32;
    const int lr = l & 31, lh = l >> 5;

    s8v bh[8], bl[8];
#pragma unroll
    for (int k0 = 0; k0 < 8; ++k0) {
        int kc = k0 * 2 + lh;
        size_t gi = ((size_t)kc * 128 + n0 + lr) << 3;
        bh[k0] = *(const s8v*)(Wh + gi);
        bl[k0] = *(const s8v*)(Wl + gi);
    }

    const int row = t >> 3;
    const int kc0 = t & 7;
    for (int rb = blockIdx.x; rb < nblk; rb += gridDim.x) {
        const int r0 = rb * 32;
        __syncthreads();  // protect LDS from previous tile's readers
        {
            int r = r0 + row;
#pragma unroll
            for (int hhalf = 0; hhalf < 2; ++hhalf) {
                int kc = kc0 + 8 * hhalf;
                float4 v0 = make_float4(0.f, 0.f, 0.f, 0.f), v1 = v0;
                if (r < n) {
                    const float4* ap = (const float4*)(A + (size_t)r * D128 + kc * 8);
                    v0 = ap[0];
                    v1 = ap[1];
                }
                s8v sh, sl;
#pragma unroll
                for (int e = 0; e < 8; ++e) {
                    float v = (e < 4) ? ((const float*)&v0)[e] : ((const float*)&v1)[e - 4];
                    unsigned short h = bf16_rne(v);
                    float fh = __uint_as_float((unsigned)h << 16);
                    sh[e] = (short)h;
                    sl[e] = (short)bf16_rne(v - fh);
                }
                lds_hi[kc][row ^ (kc & 7)] = sh;
                lds_lo[kc][row ^ (kc & 7)] = sl;
            }
        }
        __syncthreads();

        f16v acc = {0.f, 0.f, 0.f, 0.f, 0.f, 0.f, 0.f, 0.f,
                    0.f, 0.f, 0.f, 0.f, 0.f, 0.f, 0.f, 0.f};
#pragma unroll
        for (int k0 = 0; k0 < 8; ++k0) {
            int kc = k0 * 2 + lh;
            s8v ah = lds_hi[kc][lr ^ (kc & 7)];
            s8v al = lds_lo[kc][lr ^ (kc & 7)];
            acc = __builtin_amdgcn_mfma_f32_32x32x16_bf16(ah, bh[k0], acc, 0, 0, 0);
            acc = __builtin_amdgcn_mfma_f32_32x32x16_bf16(ah, bl[k0], acc, 0, 0, 0);
            acc = __builtin_amdgcn_mfma_f32_32x32x16_bf16(al, bh[k0], acc, 0, 0, 0);
        }

#pragma unroll
        for (int rg = 0; rg < 16; ++rg) {
            int grow = r0 + (rg & 3) + 8 * (rg >> 2) + 4 * lh;
            if (grow < n) Hb[(size_t)grow * D128 + n0 + lr] = bf16_rne(acc[rg]);
        }
    }
}

// Layers 1+: A bf16 (exact), 64-row tiles, persistent blocks.
__global__ __launch_bounds__(256) void gemm_mfma_bf16(
    const unsigned short* __restrict__ A, const unsigned short* __restrict__ Wh,
    const unsigned short* __restrict__ Wl, unsigned short* __restrict__ Hb,
    int n, int nblk) {
    __shared__ s8v lds_a[16][64];   // [kc][row^(kc&7)]
    const int t = threadIdx.x;
    const int l = t & 63;
    const int wv = t >> 6;
    const int n0 = wv * 32;
    const int lr = l & 31, lh = l >> 5;

    s8v bh[8], bl[8];
#pragma unroll
    for (int k0 = 0; k0 < 8; ++k0) {
        int kc = k0 * 2 + lh;
        size_t gi = ((size_t)kc * 128 + n0 + lr) << 3;
        bh[k0] = *(const s8v*)(Wh + gi);
        bl[k0] = *(const s8v*)(Wl + gi);
    }

    for (int rb = blockIdx.x; rb < nblk; rb += gridDim.x) {
        const int r0 = rb * 64;
        __syncthreads();  // protect LDS from previous tile's readers
#pragma unroll
        for (int g4 = 0; g4 < 4; ++g4) {
            int g = t * 4 + g4;
            int row = g >> 4, kc = g & 15;
            int r = r0 + row;
            s8v v = {0, 0, 0, 0, 0, 0, 0, 0};
            if (r < n) v = *(const s8v*)(A + (size_t)r * D128 + kc * 8);
            lds_a[kc][row ^ (kc & 7)] = v;
        }
        __syncthreads();

        f16v acc0 = {0.f, 0.f, 0.f, 0.f, 0.f, 0.f, 0.f, 0.f,
                     0.f, 0.f, 0.f, 0.f, 0.f, 0.f, 0.f, 0.f};
        f16v acc1 = acc0;
#pragma unroll
        for (int k0 = 0; k0 < 8; ++k0) {
            int kc = k0 * 2 + lh;
            s8v a0 = lds_a[kc][lr ^ (kc & 7)];
            s8v a1 = lds_a[kc][(32 + lr) ^ (kc & 7)];
            acc0 = __builtin_amdgcn_mfma_f32_32x32x16_bf16(a0, bh[k0], acc0, 0, 0, 0);
            acc0 = __builtin_amdgcn_mfma_f32_32x32x16_bf16(a0, bl[k0], acc0, 0, 0, 0);
            acc1 = __builtin_amdgcn_mfma_f32_32x32x16_bf16(a1, bh[k0], acc1, 0, 0, 0);
            acc1 = __builtin_amdgcn_mfma_f32_32x32x16_bf16(a1, bl[k0], acc1, 0, 0, 0);
        }

#pragma unroll
        for (int rg = 0; rg < 16; ++rg) {
            int rr = (rg & 3) + 8 * (rg >> 2) + 4 * lh;
            int grow0 = r0 + rr;
            int grow1 = r0 + 32 + rr;
            if (grow0 < n) Hb[(size_t)grow0 * D128 + n0 + lr] = bf16_rne(acc0[rg]);
            if (grow1 < n) Hb[(size_t)grow1 * D128 + n0 + lr] = bf16_rne(acc1[rg]);
        }
    }
}

// ---------------- aggregate ----------------

// One wave per dst node; 16 lanes/row (uint4 = 8 bf16/lane), 4 edges per vmem
// instr, x2 unroll. edata.x is the row BYTE offset (src<<8).
__global__ __launch_bounds__(256) void aggregate_bf16(
    const unsigned short* __restrict__ hb, const int* __restrict__ rs,
    const int2* __restrict__ edata, const float* __restrict__ bias,
    unsigned short* __restrict__ outb, float* __restrict__ outf,
    int obf, int n) {
    int wave = threadIdx.x >> 6;
    int lane = threadIdx.x & 63;
    int node = blockIdx.x * 4 + wave;
    if (node >= n) return;
    int beg = rs[node], end = rs[node + 1];
    int eg = lane >> 4;           // edge slot 0..3
    int c = lane & 15;            // 16B col chunk
    const char* base = (const char*)hb + c * 16;
    float a0[8] = {0.f, 0.f, 0.f, 0.f, 0.f, 0.f, 0.f, 0.f};
    float a1[8] = {0.f, 0.f, 0.f, 0.f, 0.f, 0.f, 0.f, 0.f};
    int i = beg;
    for (; i + 7 < end; i += 8) {
        int2 e0 = edata[i + eg];
        int2 e1 = edata[i + 4 + eg];
        uint4 p0 = *(const uint4*)(base + (unsigned)e0.x);
        uint4 p1 = *(const uint4*)(base + (unsigned)e1.x);
        float w0 = __int_as_float(e0.y), w1 = __int_as_float(e1.y);
#pragma unroll
        for (int j = 0; j < 4; ++j) {
            unsigned q0 = ((const unsigned*)&p0)[j];
            unsigned q1 = ((const unsigned*)&p1)[j];
            a0[2 * j]     = fmaf(__uint_as_float(q0 << 16), w0, a0[2 * j]);
            a0[2 * j + 1] = fmaf(__uint_as_float(q0 & 0xffff0000u), w0, a0[2 * j + 1]);
            a1[2 * j]     = fmaf(__uint_as_float(q1 << 16), w1, a1[2 * j]);
            a1[2 * j + 1] = fmaf(__uint_as_float(q1 & 0xffff0000u), w1, a1[2 * j + 1]);
        }
    }
    for (; i < end; i += 4) {
        int idx = i + eg;
        int2 e0 = (idx < end) ? edata[idx] : make_int2(0, 0);
        uint4 p0 = *(const uint4*)(base + (unsigned)e0.x);
        float w0 = __int_as_float(e0.y);
#pragma unroll
        for (int j = 0; j < 4; ++j) {
            unsigned q0 = ((const unsigned*)&p0)[j];
            a0[2 * j]     = fmaf(__uint_as_float(q0 << 16), w0, a0[2 * j]);
            a0[2 * j + 1] = fmaf(__uint_as_float(q0 & 0xffff0000u), w0, a0[2 * j + 1]);
        }
    }
#pragma unroll
    for (int k = 0; k < 8; ++k) {
        a0[k] += a1[k];
        a0[k] += __shfl_xor(a0[k], 16);
        a0[k] += __shfl_xor(a0[k], 32);
    }
    if (eg == 0) {
        float4 b0 = ((const float4*)bias)[c * 2];
        float4 b1 = ((const float4*)bias)[c * 2 + 1];
        float o[8];
        o[0] = elu1(a0[0] + b0.x);
        o[1] = elu1(a0[1] + b0.y);
        o[2] = elu1(a0[2] + b0.z);
        o[3] = elu1(a0[3] + b0.w);
        o[4] = elu1(a0[4] + b1.x);
        o[5] = elu1(a0[5] + b1.y);
        o[6] = elu1(a0[6] + b1.z);
        o[7] = elu1(a0[7] + b1.w);
        if (obf) {
            uint4 p;
            p.x = (unsigned)bf16_rne(o[0]) | ((unsigned)bf16_rne(o[1]) << 16);
            p.y = (unsigned)bf16_rne(o[2]) | ((unsigned)bf16_rne(o[3]) << 16);
            p.z = (unsigned)bf16_rne(o[4]) | ((unsigned)bf16_rne(o[5]) << 16);
            p.w = (unsigned)bf16_rne(o[6]) | ((unsigned)bf16_rne(o[7]) << 16);
            ((uint4*)(outb + (size_t)node * D128))[c] = p;
        } else {
            float4 q0 = make_float4(o[0], o[1], o[2], o[3]);
            float4 q1 = make_float4(o[4], o[5], o[6], o[7]);
            ((float4*)(outf + (size_t)node * D128))[c * 2] = q0;
            ((float4*)(outf + (size_t)node * D128))[c * 2 + 1] = q1;
        }
    }
}

extern "C" void kernel_launch(void* const* d_in, const int* in_sizes, int n_in,
                              void* d_out, int out_size, void* d_ws, size_t ws_size,
                              hipStream_t stream) {
    const float* x   = (const float*)d_in[0];
    const float* ew  = (const float*)d_in[1];
    const float* W   = (const float*)d_in[2];
    const float* b   = (const float*)d_in[3];
    const int*   src = (const int*)d_in[4];
    const int*   dst = (const int*)d_in[5];
    float* out = (float*)d_out;

    const int N = in_sizes[0] / D128;
    const int E = in_sizes[1];
    const int L = in_sizes[2] / (D128 * D128);   // == 3 here
    const int nb = (N + 255) >> BUCKET_SHIFT;
    const int hlen = nb * PBLK;

    char* ws = (char*)d_ws;
    size_t off = 0;
    auto take = [&](size_t bytes) {
        void* p = ws + off;
        off = (off + bytes + 255) & ~(size_t)255;
        return p;
    };
    float* deg_src = (float*)take((size_t)N * 4);
    int*   histT2  = (int*)take((size_t)2 * hlen * 4);  // scanned in-place
    int*   bsums   = (int*)take(1024 * 4);
    int*   rstart  = (int*)take((size_t)(N + 1) * 4);
    int2*  edata   = (int2*)take((size_t)E * 8);
    unsigned short* Hb = (unsigned short*)take((size_t)N * D128 * 2);
    unsigned short* Ab = (unsigned short*)take((size_t)N * D128 * 2);
    unsigned short* Whg = (unsigned short*)take((size_t)L * D128 * D128 * 2);
    unsigned short* Wlg = (unsigned short*)take((size_t)L * D128 * D128 * 2);
    // partition scratch aliases Ab (dead before agg0 writes Ab):
    int2* pkw = (int2*)Ab;                     // E * 8
    int2* skw = ((int2*)Ab) + E;               // E * 8

    const int chunk = (E + PBLK - 1) / PBLK;
    const int sb2 = (2 * hlen + 255) / 256;    // == 2*nb <= 1024
    const size_t part_lds = (size_t)2 * nb * 4;
    const size_t dcap_lds = (size_t)DCAP * 8;

    const int wtotal = L * D128 * D128;
    prep_w<<<(wtotal + 255) / 256, 256, 0, stream>>>(W, Whg, Wlg, wtotal);

    part_hist2<<<PBLK, 256, part_lds, stream>>>(src, dst, histT2, E, nb, chunk, hlen);
    scan_block<<<sb2, 256, 0, stream>>>(histT2, bsums, 2 * hlen);
    scan_sums<<<1, 1024, 0, stream>>>(bsums, sb2);
    part_scatter2<<<PBLK, 256, part_lds, stream>>>(src, dst, ew, histT2, bsums,
                                                   pkw, skw, E, nb, chunk, hlen);
    bucket_sumS<<<nb, 256, 0, stream>>>(skw, histT2, bsums, deg_src, E, nb, N, hlen);
    bucket_build<<<nb, 256, dcap_lds, stream>>>(pkw, histT2, bsums, deg_src,
                                                rstart, edata, E, nb, N);

    const int t32 = (N + 31) / 32;
    const int t64 = (N + 63) / 64;
    const int gemm_grid = 512;
    const int agg_grid = (N + 3) / 4;

    // layer 0: x(f32) --mfma--> Hb ; agg(+b0,ELU) --> Ab (bf16)
    gemm_mfma_f32<<<gemm_grid, 256, 0, stream>>>(x, Whg, Wlg, Hb, N, t32);
    aggregate_bf16<<<agg_grid, 256, 0, stream>>>(Hb, rstart, edata, b,
                                                 Ab, nullptr, 1, N);
    // layer 1: Ab --mfma--> Hb ; agg(+b1,ELU) --> Ab
    gemm_mfma_bf16<<<gemm_grid, 256, 0, stream>>>(Ab, Whg + D128 * D128,
                                                  Wlg + D128 * D128, Hb, N, t64);
    aggregate_bf16<<<agg_grid, 256, 0, stream>>>(Hb, rstart, edata, b + D128,
                                                 Ab, nullptr, 1, N);
    // layer 2: Ab --mfma--> Hb ; agg(+b2,ELU) --> d_out (f32)
    gemm_mfma_bf16<<<gemm_grid, 256, 0, stream>>>(Ab, Whg + 2 * D128 * D128,
                                                  Wlg + 2 * D128 * D128, Hb, N, t64);
    aggregate_bf16<<<agg_grid, 256, 0, stream>>>(Hb, rstart, edata, b + 2 * D128,
                                                 nullptr, out, 0, N);
}